// Round 1
// baseline (3865.088 us; speedup 1.0000x reference)
//
#include <hip/hip_runtime.h>
#include <math.h>

#define Bb 256
#define Tt 256
#define Ff 128
#define Hh 512
#define KTOT 768   // 2F+H
#define NC 2048    // 4*H  (gate cols: colH*4 + {r,z,i_n,h_n})
#define BH (Bb * Hh)

typedef unsigned short u16;
typedef unsigned int   u32;
typedef __attribute__((ext_vector_type(8))) short s8v;   // 8 bf16 (4 VGPRs)
typedef __attribute__((ext_vector_type(4))) float f4v;   // 4 fp32 acc

// ---------------- ws layout (bytes) ----------------
// gamma  : u16 [Tt*Bb*Hh]        = 67,108,864 B   [T,B,H]
// xrep   : u16 [Bb*Tt*Ff]        = 16,777,216 B
// mbf    : u16 [Bb*Tt*Ff]        = 16,777,216 B
// wfrag  : u16 [NC*KTOT]         =  3,145,728 B   frag-major
// biasc  : f32 [NC]              =      8,192 B
// hg     : u16 [2*Bb*Hh]         =    524,288 B   decayed-h bf16 ping-pong
// bar    : i32 [16*16]           =      1,024 B   per-by-group barrier counters
// total ≈ 104.3 MB
#define OFF_GAMMA 0ull
#define OFF_XREP  (OFF_GAMMA + 67108864ull)
#define OFF_MBF   (OFF_XREP  + 16777216ull)
#define OFF_WFRAG (OFF_MBF   + 16777216ull)
#define OFF_BIASC (OFF_WFRAG + 3145728ull)
#define OFF_HG    (OFF_BIASC + 8192ull)
#define OFF_BAR   (OFF_HG    + 524288ull)

__device__ __forceinline__ u16 f2b(float x) {   // fp32 -> bf16 RNE
    u32 u = __float_as_uint(x);
    return (u16)((u + 0x7FFFu + ((u >> 16) & 1u)) >> 16);
}
__device__ __forceinline__ float b2f(u16 b) {
    return __uint_as_float(((u32)b) << 16);
}

__global__ __launch_bounds__(256) void k_zero(float* p, int n) {
    int i = blockIdx.x * 256 + threadIdx.x;
    if (i < n) p[i] = 0.f;
}

__device__ __forceinline__ float xrep_one(float x, float m, float d, float l,
                                          float w, float bb, float em) {
    float gx = expf(-fmaxf(d * w + bb, 0.f));
    float xh = gx * l + (1.f - gx) * em;
    return m * x + (1.f - m) * xh;
}

// Elementwise precompute: x_rep and m in bf16, layout [B][T][F].
__global__ __launch_bounds__(256) void k_prep(const float* __restrict__ values,
                                              const float* __restrict__ masks,
                                              const float* __restrict__ deltas,
                                              const float* __restrict__ locf,
                                              const float* __restrict__ emean,
                                              const float* __restrict__ wx,
                                              const float* __restrict__ bxp,
                                              u16* __restrict__ xrep,
                                              u16* __restrict__ mbf) {
    int idx = blockIdx.x * 256 + threadIdx.x;   // < B*T*F/4
    int e = idx * 4;
    int f = e & 127;
    float4 xv = *(const float4*)&values[e];
    float4 mv = *(const float4*)&masks[e];
    float4 dv = *(const float4*)&deltas[e];
    float4 lv = *(const float4*)&locf[e];
    float4 wv = *(const float4*)&wx[f];
    float4 bv = *(const float4*)&bxp[f];
    float4 ev = *(const float4*)&emean[f];
    u16 o[4], mo[4];
    o[0] = f2b(xrep_one(xv.x, mv.x, dv.x, lv.x, wv.x, bv.x, ev.x));
    o[1] = f2b(xrep_one(xv.y, mv.y, dv.y, lv.y, wv.y, bv.y, ev.y));
    o[2] = f2b(xrep_one(xv.z, mv.z, dv.z, lv.z, wv.z, bv.z, ev.z));
    o[3] = f2b(xrep_one(xv.w, mv.w, dv.w, lv.w, wv.w, bv.w, ev.w));
    mo[0] = f2b(mv.x); mo[1] = f2b(mv.y); mo[2] = f2b(mv.z); mo[3] = f2b(mv.w);
    *(uint2*)&xrep[e] = *(uint2*)o;
    *(uint2*)&mbf[e]  = *(uint2*)mo;
}

// Combined weight, frag-major bf16 (unchanged from previous round).
__global__ __launch_bounds__(256) void k_wcomb(const float* __restrict__ W_ih,
                                               const float* __restrict__ W_hh,
                                               const float* __restrict__ b_ih,
                                               const float* __restrict__ b_hh,
                                               u16* __restrict__ wfrag,
                                               float* __restrict__ biasc) {
    int G = blockIdx.x * 256 + threadIdx.x;   // < NC*KTOT/8 = 196608
    int lane = G & 63;
    int q = G >> 6;
    int ki = q % 24; q /= 24;
    int nt = q & 1;  q >>= 1;
    int wv = q & 3;  q >>= 2;
    int bx = q;                                // 0..15
    int c = bx * 128 + wv * 32 + nt * 16 + (lane & 15);
    int kbase = ki * 32 + (lane >> 4) * 8;
    int g = c & 3, jH = c >> 2;
    u16 o[8];
#pragma unroll
    for (int j = 0; j < 8; ++j) {
        int k = kbase + j;
        float w;
        if (g < 3) {
            w = W_ih[(size_t)(g * Hh + jH) * KTOT + k];
            if (g < 2 && k >= Ff && k < Ff + Hh) w += W_hh[(size_t)(g * Hh + jH) * Hh + (k - Ff)];
        } else {
            w = (k >= Ff && k < Ff + Hh) ? W_hh[(size_t)(2 * Hh + jH) * Hh + (k - Ff)] : 0.f;
        }
        o[j] = f2b(w);
    }
    *(uint4*)&wfrag[(size_t)G * 8] = *(uint4*)o;
    if (ki == 0 && (lane >> 4) == 0) {
        float bv;
        if (g == 0)      bv = b_ih[jH] + b_hh[jH];
        else if (g == 1) bv = b_ih[Hh + jH] + b_hh[Hh + jH];
        else if (g == 2) bv = b_ih[2 * Hh + jH];
        else             bv = b_hh[2 * Hh + jH];
        biasc[c] = bv;
    }
}

// gamma_h precompute (fp32 compute, bf16 store): [T*B rows] x [H cols], K=128.
__global__ __launch_bounds__(256) void k_gamma(const float* __restrict__ deltas,
                                               const float* __restrict__ Wh,
                                               const float* __restrict__ bh,
                                               u16* __restrict__ gamma) {
    __shared__ float A_s[64][68];
    __shared__ float B_s[64][68];
    int tid = threadIdx.x;
    int tx = tid & 15, ty = tid >> 4;
    int bt0 = blockIdx.x * 64;
    int c0  = blockIdx.y * 64;

    float acc[4][4];
#pragma unroll
    for (int i = 0; i < 4; ++i)
#pragma unroll
        for (int j = 0; j < 4; ++j) acc[i][j] = 0.f;

    for (int kc = 0; kc < 2; ++kc) {
#pragma unroll
        for (int s = 0; s < 4; ++s) {
            int v = tid + s * 256;
            int row = v >> 4, c4 = v & 15, kk = c4 * 4;
            int bt = bt0 + row;
            int b = bt & 255, tt = bt >> 8;
            float4 a = *(const float4*)&deltas[b * (Tt * Ff) + tt * Ff + kc * 64 + kk];
            *(float4*)&A_s[row][kk] = a;
        }
#pragma unroll
        for (int s = 0; s < 4; ++s) {
            int v = tid + s * 256;
            int col = v >> 4, c4 = v & 15, kk = c4 * 4;
            float4 w = *(const float4*)&Wh[(c0 + col) * Ff + kc * 64 + kk];
            *(float4*)&B_s[col][kk] = w;
        }
        __syncthreads();
#pragma unroll
        for (int kk = 0; kk < 64; kk += 4) {
            float4 a[4], b[4];
#pragma unroll
            for (int i = 0; i < 4; ++i) a[i] = *(const float4*)&A_s[4 * ty + i][kk];
#pragma unroll
            for (int j = 0; j < 4; ++j) b[j] = *(const float4*)&B_s[4 * tx + j][kk];
#pragma unroll
            for (int i = 0; i < 4; ++i)
#pragma unroll
                for (int j = 0; j < 4; ++j) {
                    acc[i][j] += a[i].x * b[j].x;
                    acc[i][j] += a[i].y * b[j].y;
                    acc[i][j] += a[i].z * b[j].z;
                    acc[i][j] += a[i].w * b[j].w;
                }
        }
        __syncthreads();
    }
#pragma unroll
    for (int i = 0; i < 4; ++i) {
        int bt = bt0 + 4 * ty + i;
        u16 o[4];
#pragma unroll
        for (int j = 0; j < 4; ++j) {
            int col = c0 + 4 * tx + j;
            float x = acc[i][j] + bh[col];
            o[j] = f2b(expf(-fmaxf(x, 0.f)));
        }
        *(uint2*)&gamma[(size_t)bt * Hh + c0 + 4 * tx] = *(uint2*)o;
    }
}

// ---------------------------------------------------------------------------
// Persistent scan kernel: one launch for all T steps.
// Grid (16,16) = 256 blocks (1/CU), 256 threads. Block (bx,by): rows by*16..+16,
// gate cols bx*128..+128. B-fragments register-resident across all steps.
// Cross-block dependency per step is only h rows by*16..+16, produced by the
// 16 blocks sharing `by` -> per-by-group device-scope barrier.
// h state: decayed h (h(t-1)*gamma_t) kept f32 in registers per thread (fixed
// (row,col) mapping), mirrored as bf16 in global hg ping-pong for staging.
// ---------------------------------------------------------------------------
__global__ __launch_bounds__(256, 1) void k_scan(const u16* __restrict__ xrep,
                                                 const u16* __restrict__ mbf,
                                                 const u16* __restrict__ gamma,
                                                 const u16* __restrict__ wfrag,
                                                 const float* __restrict__ biasc,
                                                 u16* __restrict__ hgbuf,
                                                 int* __restrict__ bar,
                                                 float* __restrict__ hs,
                                                 float* __restrict__ hlast) {
    __shared__ u16  A_s[24 * 64 * 8];   // 24.6 KB, frag-major A tile
    __shared__ float E_s[16][132];      // 8.45 KB, gate preacts

    int tid = threadIdx.x;
    int lane = tid & 63, w = tid >> 6;
    int bx = blockIdx.x;   // col group (16)
    int by = blockIdx.y;   // row group (16)
    int r0 = by * 16;

    // ---- B fragments: loaded ONCE, resident in VGPRs for all 256 steps ----
    uint4 Bf[2][24];
    const uint4* wf4 = (const uint4*)wfrag;
#pragma unroll
    for (int nt = 0; nt < 2; ++nt)
#pragma unroll
        for (int ki = 0; ki < 24; ++ki)
            Bf[nt][ki] = wf4[(size_t)((((bx * 4 + w) * 2 + nt) * 24 + ki) * 64 + lane)];

    // ---- fixed epilogue mapping per thread: row bl, h-cols JH0, JH0+1 ----
    int bl = tid >> 4, jh0 = (tid & 15) * 2;
    int eb = r0 + bl;
    int JH0 = bx * 32 + jh0;
    float hreg0 = 0.f, hreg1 = 0.f;   // decayed h = h(t-1)*gamma_t, f32 (h0 = 0)

    for (int t = 0; t < Tt; ++t) {
        const u16* hgr = hgbuf + (t & 1) * BH;

        // ---- stage A tile (16 rows x 768 K bf16) frag-major ----
        // per wave: ki = s*4+w is uniform, so region select is wave-uniform
#pragma unroll
        for (int s = 0; s < 6; ++s) {
            int G = tid + s * 256;            // < 1536
            int ki = G >> 6;
            int ls = G & 63;
            int row = ls & 15;
            int kbase = ki * 32 + (ls >> 4) * 8;
            int b = r0 + row;
            uint4 out;
            if (kbase < 128) {
                out = *(const uint4*)&xrep[(size_t)b * (Tt * Ff) + t * Ff + kbase];
            } else if (kbase < 640) {
                out = *(const uint4*)&hgr[b * Hh + (kbase - 128)];   // pre-decayed bf16
            } else {
                out = *(const uint4*)&mbf[(size_t)b * (Tt * Ff) + t * Ff + (kbase - 640)];
            }
            *(uint4*)&A_s[G * 8] = out;
        }
        __syncthreads();

        // ---- MFMA: 24 k-iters x 2 N-tiles ----
        f4v acc0 = {0.f, 0.f, 0.f, 0.f};
        f4v acc1 = {0.f, 0.f, 0.f, 0.f};
#pragma unroll
        for (int ki = 0; ki < 24; ++ki) {
            s8v a = *(const s8v*)&A_s[(ki * 64 + lane) * 8];
            acc0 = __builtin_amdgcn_mfma_f32_16x16x32_bf16(a, __builtin_bit_cast(s8v, Bf[0][ki]), acc0, 0, 0, 0);
            acc1 = __builtin_amdgcn_mfma_f32_16x16x32_bf16(a, __builtin_bit_cast(s8v, Bf[1][ki]), acc1, 0, 0, 0);
        }

        // ---- C layout (row=(lane>>4)*4+reg, col=lane&15) -> LDS ----
        {
            int colb = w * 32 + (lane & 15);
            int rq = (lane >> 4) * 4;
#pragma unroll
            for (int r = 0; r < 4; ++r) {
                E_s[rq + r][colb]      = acc0[r];
                E_s[rq + r][colb + 16] = acc1[r];
            }
        }
        __syncthreads();

        // ---- gates + h update: 2 consecutive h-cols per thread ----
        float4 p0  = *(const float4*)&E_s[bl][jh0 * 4];
        float4 p1  = *(const float4*)&E_s[bl][jh0 * 4 + 4];
        float4 bi0 = *(const float4*)&biasc[JH0 * 4];
        float4 bi1 = *(const float4*)&biasc[JH0 * 4 + 4];
        float rg0 = 1.f / (1.f + expf(-(p0.x + bi0.x)));
        float zz0 = 1.f / (1.f + expf(-(p0.y + bi0.y)));
        float nn0 = tanhf(p0.z + bi0.z + rg0 * (p0.w + bi0.w));
        float hn0 = (1.f - zz0) * nn0 + zz0 * hreg0;
        float rg1 = 1.f / (1.f + expf(-(p1.x + bi1.x)));
        float zz1 = 1.f / (1.f + expf(-(p1.y + bi1.y)));
        float nn1 = tanhf(p1.z + bi1.z + rg1 * (p1.w + bi1.w));
        float hn1 = (1.f - zz1) * nn1 + zz1 * hreg1;

        float2 hn2; hn2.x = hn0; hn2.y = hn1;
        *(float2*)&hs[(size_t)eb * (Tt * Hh) + (size_t)t * Hh + JH0] = hn2;

        if (t < Tt - 1) {
            // decay with gamma(t+1); keep f32 in regs, bf16 mirror to global
            u32 g = *(const u32*)&gamma[((size_t)(t + 1) * Bb + eb) * Hh + JH0];
            hreg0 = hn0 * b2f((u16)(g & 0xffffu));
            hreg1 = hn1 * b2f((u16)(g >> 16));
            u16* hgw = hgbuf + ((t + 1) & 1) * BH;
            u32 o = (u32)f2b(hreg0) | ((u32)f2b(hreg1) << 16);
            *(u32*)&hgw[eb * Hh + JH0] = o;

            // ---- per-by-group barrier (16 blocks), device scope ----
            __syncthreads();
            if (tid == 0) {
                int* c = &bar[by * 16];
                __hip_atomic_fetch_add(c, 1, __ATOMIC_RELEASE, __HIP_MEMORY_SCOPE_AGENT);
                int target = 16 * (t + 1);
                int spins = 0;
                while (__hip_atomic_load(c, __ATOMIC_RELAXED, __HIP_MEMORY_SCOPE_AGENT) < target) {
                    __builtin_amdgcn_s_sleep(1);
                    if (++spins > (1 << 20)) break;   // emergency escape (never in practice)
                }
                (void)__hip_atomic_load(c, __ATOMIC_ACQUIRE, __HIP_MEMORY_SCOPE_AGENT);
            }
            __syncthreads();
        } else {
            *(float2*)&hlast[eb * Hh + JH0] = hn2;
        }
    }
}

extern "C" void kernel_launch(void* const* d_in, const int* in_sizes, int n_in,
                              void* d_out, int out_size, void* d_ws, size_t ws_size,
                              hipStream_t stream) {
    const float* values = (const float*)d_in[0];
    const float* masks  = (const float*)d_in[1];
    const float* deltas = (const float*)d_in[2];
    const float* emean  = (const float*)d_in[3];
    const float* locf   = (const float*)d_in[4];
    const float* wx     = (const float*)d_in[5];
    const float* bxp    = (const float*)d_in[6];
    const float* Wh     = (const float*)d_in[7];
    const float* bh     = (const float*)d_in[8];
    const float* W_ih   = (const float*)d_in[9];
    const float* W_hh   = (const float*)d_in[10];
    const float* b_ih   = (const float*)d_in[11];
    const float* b_hh   = (const float*)d_in[12];

    char* wsb   = (char*)d_ws;
    u16*  gamma = (u16*)(wsb + OFF_GAMMA);
    u16*  xrep  = (u16*)(wsb + OFF_XREP);
    u16*  mbf   = (u16*)(wsb + OFF_MBF);
    u16*  wfrag = (u16*)(wsb + OFF_WFRAG);
    float* biasc = (float*)(wsb + OFF_BIASC);
    u16*  hg    = (u16*)(wsb + OFF_HG);
    int*  bar   = (int*)(wsb + OFF_BAR);
    float* hs    = (float*)d_out;
    float* hlast = hs + (size_t)Bb * Tt * Hh;

    // zero hg ping-pong (both halves) + barrier counters
    k_zero<<<513, 256, 0, stream>>>((float*)(wsb + OFF_HG), (524288 + 1024) / 4);
    k_prep<<<(Bb * Tt * Ff / 4) / 256, 256, 0, stream>>>(values, masks, deltas, locf,
                                                         emean, wx, bxp, xrep, mbf);
    k_gamma<<<dim3((Tt * Bb) / 64, Hh / 64), 256, 0, stream>>>(deltas, Wh, bh, gamma);
    k_wcomb<<<(NC * KTOT / 8) / 256, 256, 0, stream>>>(W_ih, W_hh, b_ih, b_hh, wfrag, biasc);

    k_scan<<<dim3(16, 16), 256, 0, stream>>>(xrep, mbf, gamma, wfrag, biasc,
                                             hg, bar, hs, hlast);
}

// Round 3
// 1927.759 us; speedup vs baseline: 2.0050x; 2.0050x over previous
//
#include <hip/hip_runtime.h>
#include <math.h>

#define Bb 256
#define Tt 256
#define Ff 128
#define Hh 512
#define KTOT 768   // 2F+H
#define NC 2048    // 4*H  (gate cols: colH*4 + {r,z,i_n,h_n})

typedef unsigned short u16;
typedef unsigned int   u32;
typedef unsigned long long u64;
typedef __attribute__((ext_vector_type(8))) short s8v;   // 8 bf16 (4 VGPRs)
typedef __attribute__((ext_vector_type(4))) float f4v;   // 4 fp32 acc

// ---------------- ws layout (bytes) ----------------
// gamma  : u16 [Tt*Bb*Hh]        = 67,108,864 B   [T,B,H]
// xrep   : u16 [Bb*Tt*Ff]        = 16,777,216 B
// mbf    : u16 [Bb*Tt*Ff]        = 16,777,216 B
// wfrag  : u16 [NC*KTOT]         =  3,145,728 B   frag-major
// biasc  : f32 [NC]              =      8,192 B
// bar    : i32 [16*32]           =      2,048 B   per-by-group counters (128B apart)
// total ≈ 103.8 MB
#define OFF_GAMMA 0ull
#define OFF_XREP  (OFF_GAMMA + 67108864ull)
#define OFF_MBF   (OFF_XREP  + 16777216ull)
#define OFF_WFRAG (OFF_MBF   + 16777216ull)
#define OFF_BIASC (OFF_WFRAG + 3145728ull)
#define OFF_BAR   (OFF_BIASC + 8192ull)

__device__ __forceinline__ u16 f2b(float x) {   // fp32 -> bf16 RNE
    u32 u = __float_as_uint(x);
    return (u16)((u + 0x7FFFu + ((u >> 16) & 1u)) >> 16);
}
__device__ __forceinline__ float b2f(u16 b) {
    return __uint_as_float(((u32)b) << 16);
}

__global__ __launch_bounds__(256) void k_zero(int* p, int n) {
    int i = blockIdx.x * 256 + threadIdx.x;
    if (i < n) p[i] = 0;
}

__device__ __forceinline__ float xrep_one(float x, float m, float d, float l,
                                          float w, float bb, float em) {
    float gx = expf(-fmaxf(d * w + bb, 0.f));
    float xh = gx * l + (1.f - gx) * em;
    return m * x + (1.f - m) * xh;
}

// Elementwise precompute: x_rep and m in bf16, layout [B][T][F].
__global__ __launch_bounds__(256) void k_prep(const float* __restrict__ values,
                                              const float* __restrict__ masks,
                                              const float* __restrict__ deltas,
                                              const float* __restrict__ locf,
                                              const float* __restrict__ emean,
                                              const float* __restrict__ wx,
                                              const float* __restrict__ bxp,
                                              u16* __restrict__ xrep,
                                              u16* __restrict__ mbf) {
    int idx = blockIdx.x * 256 + threadIdx.x;   // < B*T*F/4
    int e = idx * 4;
    int f = e & 127;
    float4 xv = *(const float4*)&values[e];
    float4 mv = *(const float4*)&masks[e];
    float4 dv = *(const float4*)&deltas[e];
    float4 lv = *(const float4*)&locf[e];
    float4 wv = *(const float4*)&wx[f];
    float4 bv = *(const float4*)&bxp[f];
    float4 ev = *(const float4*)&emean[f];
    u16 o[4], mo[4];
    o[0] = f2b(xrep_one(xv.x, mv.x, dv.x, lv.x, wv.x, bv.x, ev.x));
    o[1] = f2b(xrep_one(xv.y, mv.y, dv.y, lv.y, wv.y, bv.y, ev.y));
    o[2] = f2b(xrep_one(xv.z, mv.z, dv.z, lv.z, wv.z, bv.z, ev.z));
    o[3] = f2b(xrep_one(xv.w, mv.w, dv.w, lv.w, wv.w, bv.w, ev.w));
    mo[0] = f2b(mv.x); mo[1] = f2b(mv.y); mo[2] = f2b(mv.z); mo[3] = f2b(mv.w);
    *(uint2*)&xrep[e] = *(uint2*)o;
    *(uint2*)&mbf[e]  = *(uint2*)mo;
}

// Combined weight, frag-major bf16 (unchanged).
__global__ __launch_bounds__(256) void k_wcomb(const float* __restrict__ W_ih,
                                               const float* __restrict__ W_hh,
                                               const float* __restrict__ b_ih,
                                               const float* __restrict__ b_hh,
                                               u16* __restrict__ wfrag,
                                               float* __restrict__ biasc) {
    int G = blockIdx.x * 256 + threadIdx.x;   // < NC*KTOT/8 = 196608
    int lane = G & 63;
    int q = G >> 6;
    int ki = q % 24; q /= 24;
    int nt = q & 1;  q >>= 1;
    int wv = q & 3;  q >>= 2;
    int bx = q;                                // 0..15
    int c = bx * 128 + wv * 32 + nt * 16 + (lane & 15);
    int kbase = ki * 32 + (lane >> 4) * 8;
    int g = c & 3, jH = c >> 2;
    u16 o[8];
#pragma unroll
    for (int j = 0; j < 8; ++j) {
        int k = kbase + j;
        float w;
        if (g < 3) {
            w = W_ih[(size_t)(g * Hh + jH) * KTOT + k];
            if (g < 2 && k >= Ff && k < Ff + Hh) w += W_hh[(size_t)(g * Hh + jH) * Hh + (k - Ff)];
        } else {
            w = (k >= Ff && k < Ff + Hh) ? W_hh[(size_t)(2 * Hh + jH) * Hh + (k - Ff)] : 0.f;
        }
        o[j] = f2b(w);
    }
    *(uint4*)&wfrag[(size_t)G * 8] = *(uint4*)o;
    if (ki == 0 && (lane >> 4) == 0) {
        float bv;
        if (g == 0)      bv = b_ih[jH] + b_hh[jH];
        else if (g == 1) bv = b_ih[Hh + jH] + b_hh[Hh + jH];
        else if (g == 2) bv = b_ih[2 * Hh + jH];
        else             bv = b_hh[2 * Hh + jH];
        biasc[c] = bv;
    }
}

// gamma_h precompute (fp32 compute, bf16 store): [T*B rows] x [H cols], K=128.
__global__ __launch_bounds__(256) void k_gamma(const float* __restrict__ deltas,
                                               const float* __restrict__ Wh,
                                               const float* __restrict__ bh,
                                               u16* __restrict__ gamma) {
    __shared__ float A_s[64][68];
    __shared__ float B_s[64][68];
    int tid = threadIdx.x;
    int tx = tid & 15, ty = tid >> 4;
    int bt0 = blockIdx.x * 64;
    int c0  = blockIdx.y * 64;

    float acc[4][4];
#pragma unroll
    for (int i = 0; i < 4; ++i)
#pragma unroll
        for (int j = 0; j < 4; ++j) acc[i][j] = 0.f;

    for (int kc = 0; kc < 2; ++kc) {
#pragma unroll
        for (int s = 0; s < 4; ++s) {
            int v = tid + s * 256;
            int row = v >> 4, c4 = v & 15, kk = c4 * 4;
            int bt = bt0 + row;
            int b = bt & 255, tt = bt >> 8;
            float4 a = *(const float4*)&deltas[b * (Tt * Ff) + tt * Ff + kc * 64 + kk];
            *(float4*)&A_s[row][kk] = a;
        }
#pragma unroll
        for (int s = 0; s < 4; ++s) {
            int v = tid + s * 256;
            int col = v >> 4, c4 = v & 15, kk = c4 * 4;
            float4 w = *(const float4*)&Wh[(c0 + col) * Ff + kc * 64 + kk];
            *(float4*)&B_s[col][kk] = w;
        }
        __syncthreads();
#pragma unroll
        for (int kk = 0; kk < 64; kk += 4) {
            float4 a[4], b[4];
#pragma unroll
            for (int i = 0; i < 4; ++i) a[i] = *(const float4*)&A_s[4 * ty + i][kk];
#pragma unroll
            for (int j = 0; j < 4; ++j) b[j] = *(const float4*)&B_s[4 * tx + j][kk];
#pragma unroll
            for (int i = 0; i < 4; ++i)
#pragma unroll
                for (int j = 0; j < 4; ++j) {
                    acc[i][j] += a[i].x * b[j].x;
                    acc[i][j] += a[i].y * b[j].y;
                    acc[i][j] += a[i].z * b[j].z;
                    acc[i][j] += a[i].w * b[j].w;
                }
        }
        __syncthreads();
    }
#pragma unroll
    for (int i = 0; i < 4; ++i) {
        int bt = bt0 + 4 * ty + i;
        u16 o[4];
#pragma unroll
        for (int j = 0; j < 4; ++j) {
            int col = c0 + 4 * tx + j;
            float x = acc[i][j] + bh[col];
            o[j] = f2b(expf(-fmaxf(x, 0.f)));
        }
        *(uint2*)&gamma[(size_t)bt * Hh + c0 + 4 * tx] = *(uint2*)o;
    }
}

// ---------------------------------------------------------------------------
// Persistent scan kernel, v3: watertight cross-XCD exchange.
// - h published via global_atomic_swap_x2 into hs (d_out) -> RMWs execute at
//   the MALL coherence point; vmcnt-ack == visible. No separate hg buffer.
// - Consumers read h from hs[:, t, :]: addresses virgin within this launch ->
//   guaranteed cache miss -> served by MALL. No scope flags, no invalidates.
// - Spin probe is fetch_add(c, 0) (RMW-read, cannot be stale).
// - gamma for staging and epilogue prefetched into regs before the barrier;
//   x/m A-tile regions staged before the barrier (overlap the epilogue).
// ---------------------------------------------------------------------------
__global__ __launch_bounds__(256, 1) void k_scan(const u16* __restrict__ xrep,
                                                 const u16* __restrict__ mbf,
                                                 const u16* __restrict__ gamma,
                                                 const u16* __restrict__ wfrag,
                                                 const float* __restrict__ biasc,
                                                 int* __restrict__ bar,
                                                 float* __restrict__ hs,
                                                 float* __restrict__ hlast) {
    __shared__ u16  A_s[24 * 64 * 8];   // 24.6 KB, frag-major A tile
    __shared__ float E_s[16][132];      // 8.45 KB, gate preacts

    int tid = threadIdx.x;
    int lane = tid & 63, w = tid >> 6;
    int bx = blockIdx.x;   // col group (16)
    int by = blockIdx.y;   // row group (16)
    int r0 = by * 16;

    // ---- B fragments: loaded once (compiler may re-materialize; L2-hit) ----
    uint4 Bf[2][24];
    const uint4* wf4 = (const uint4*)wfrag;
#pragma unroll
    for (int nt = 0; nt < 2; ++nt)
#pragma unroll
        for (int ki = 0; ki < 24; ++ki)
            Bf[nt][ki] = wf4[(size_t)((((bx * 4 + w) * 2 + nt) * 24 + ki) * 64 + lane)];

    // staging geometry: G = tid + s*256, ki = s*4 + w (wave-uniform),
    // row = lane&15, kbase = ki*32 + (lane>>4)*8.
    int srow = lane & 15;
    int koff = (lane >> 4) * 8;

    // ---- fixed epilogue mapping per thread: row bl, h-cols JH0, JH0+1 ----
    int bl = tid >> 4, jh0 = (tid & 15) * 2;
    int eb = r0 + bl;
    int JH0 = bx * 32 + jh0;
    float hreg0 = 0.f, hreg1 = 0.f;   // decayed h = h(t-1)*gamma_t, f32 (h0 = 0)

    // ---- prologue: stage A tile for t=0 (h region = 0) ----
    {
        int kb = w * 32 + koff;
        *(uint4*)&A_s[tid * 8] =
            *(const uint4*)&xrep[(size_t)(r0 + srow) * (Tt * Ff) + 0 * Ff + kb];
        *(uint4*)&A_s[(tid + 5 * 256) * 8] =
            *(const uint4*)&mbf[(size_t)(r0 + srow) * (Tt * Ff) + 0 * Ff + kb];
        uint4 z; z.x = 0; z.y = 0; z.z = 0; z.w = 0;
#pragma unroll
        for (int s = 1; s <= 4; ++s)
            *(uint4*)&A_s[(tid + s * 256) * 8] = z;
    }
    __syncthreads();

    for (int t = 0; t < Tt; ++t) {
        // ---- MFMA: 24 k-iters x 2 N-tiles ----
        f4v acc0 = {0.f, 0.f, 0.f, 0.f};
        f4v acc1 = {0.f, 0.f, 0.f, 0.f};
#pragma unroll
        for (int ki = 0; ki < 24; ++ki) {
            s8v a = *(const s8v*)&A_s[(ki * 64 + lane) * 8];
            acc0 = __builtin_amdgcn_mfma_f32_16x16x32_bf16(a, __builtin_bit_cast(s8v, Bf[0][ki]), acc0, 0, 0, 0);
            acc1 = __builtin_amdgcn_mfma_f32_16x16x32_bf16(a, __builtin_bit_cast(s8v, Bf[1][ki]), acc1, 0, 0, 0);
        }

        // ---- C layout (row=(lane>>4)*4+reg, col=lane&15) -> LDS ----
        {
            int colb = w * 32 + (lane & 15);
            int rq = (lane >> 4) * 4;
#pragma unroll
            for (int r = 0; r < 4; ++r) {
                E_s[rq + r][colb]      = acc0[r];
                E_s[rq + r][colb + 16] = acc1[r];
            }
        }
        __syncthreads();   // E_s ready; A_s free (all MFMA reads done)

        // ---- barrier-independent prefetch for t+1: x/m -> A_s, gamma -> regs ----
        uint4 g4[4];
        if (t < Tt - 1) {
            int kb = w * 32 + koff;
            *(uint4*)&A_s[tid * 8] =
                *(const uint4*)&xrep[(size_t)(r0 + srow) * (Tt * Ff) + (t + 1) * Ff + kb];
            *(uint4*)&A_s[(tid + 5 * 256) * 8] =
                *(const uint4*)&mbf[(size_t)(r0 + srow) * (Tt * Ff) + (t + 1) * Ff + kb];
#pragma unroll
            for (int s = 1; s <= 4; ++s) {
                int kh = (s * 4 + w) * 32 + koff - 128;   // 0..511
                g4[s - 1] = *(const uint4*)&gamma[((size_t)(t + 1) * Bb + (r0 + srow)) * Hh + kh];
            }
        }

        // ---- gates + h update: 2 consecutive h-cols per thread ----
        float4 p0  = *(const float4*)&E_s[bl][jh0 * 4];
        float4 p1  = *(const float4*)&E_s[bl][jh0 * 4 + 4];
        float4 bi0 = *(const float4*)&biasc[JH0 * 4];
        float4 bi1 = *(const float4*)&biasc[JH0 * 4 + 4];
        float rg0 = 1.f / (1.f + expf(-(p0.x + bi0.x)));
        float zz0 = 1.f / (1.f + expf(-(p0.y + bi0.y)));
        float nn0 = tanhf(p0.z + bi0.z + rg0 * (p0.w + bi0.w));
        float hn0 = (1.f - zz0) * nn0 + zz0 * hreg0;
        float rg1 = 1.f / (1.f + expf(-(p1.x + bi1.x)));
        float zz1 = 1.f / (1.f + expf(-(p1.y + bi1.y)));
        float nn1 = tanhf(p1.z + bi1.z + rg1 * (p1.w + bi1.w));
        float hn1 = (1.f - zz1) * nn1 + zz1 * hreg1;

        // publish h_t via RMW (executes at MALL; doubles as the output store)
        union { float f[2]; u64 u; } pk;
        pk.f[0] = hn0; pk.f[1] = hn1;
        __hip_atomic_exchange((u64*)&hs[(size_t)eb * (Tt * Hh) + (size_t)t * Hh + JH0],
                              pk.u, __ATOMIC_RELAXED, __HIP_MEMORY_SCOPE_AGENT);

        if (t < Tt - 1) {
            // decay for next step: f32 in regs (epilogue path)
            u32 g = *(const u32*)&gamma[((size_t)(t + 1) * Bb + eb) * Hh + JH0];
            hreg0 = hn0 * b2f((u16)(g & 0xffffu));
            hreg1 = hn1 * b2f((u16)(g >> 16));

            // ---- group barrier: all swaps drained, then RMW counter ----
            asm volatile("s_waitcnt vmcnt(0)" ::: "memory");
            __syncthreads();
            if (tid == 0) {
                int* c = &bar[by * 32];
                __hip_atomic_fetch_add(c, 1, __ATOMIC_RELAXED, __HIP_MEMORY_SCOPE_AGENT);
                int target = 16 * (t + 1);
                int iters = 0;
                while (__hip_atomic_fetch_add(c, 0, __ATOMIC_RELAXED,
                                              __HIP_MEMORY_SCOPE_AGENT) < target) {
                    __builtin_amdgcn_s_sleep(8);
                    if (++iters > (1 << 22)) break;   // visible-failure escape
                }
            }
            __syncthreads();

            // ---- stage t+1 h region: virgin hs addresses x prefetched gamma ----
#pragma unroll
            for (int s = 1; s <= 4; ++s) {
                int kh = (s * 4 + w) * 32 + koff - 128;   // 0..511
                const float* hp = &hs[(size_t)(r0 + srow) * (Tt * Hh) + (size_t)t * Hh + kh];
                float4 h0 = *(const float4*)hp;
                float4 h1 = *(const float4*)(hp + 4);
                u16 g[8];
                *(uint4*)g = g4[s - 1];
                u16 o[8];
                o[0] = f2b(h0.x * b2f(g[0])); o[1] = f2b(h0.y * b2f(g[1]));
                o[2] = f2b(h0.z * b2f(g[2])); o[3] = f2b(h0.w * b2f(g[3]));
                o[4] = f2b(h1.x * b2f(g[4])); o[5] = f2b(h1.y * b2f(g[5]));
                o[6] = f2b(h1.z * b2f(g[6])); o[7] = f2b(h1.w * b2f(g[7]));
                *(uint4*)&A_s[(tid + s * 256) * 8] = *(uint4*)o;
            }
            __syncthreads();
        } else {
            float2 hn2; hn2.x = hn0; hn2.y = hn1;
            *(float2*)&hlast[eb * Hh + JH0] = hn2;
        }
    }
}

extern "C" void kernel_launch(void* const* d_in, const int* in_sizes, int n_in,
                              void* d_out, int out_size, void* d_ws, size_t ws_size,
                              hipStream_t stream) {
    const float* values = (const float*)d_in[0];
    const float* masks  = (const float*)d_in[1];
    const float* deltas = (const float*)d_in[2];
    const float* emean  = (const float*)d_in[3];
    const float* locf   = (const float*)d_in[4];
    const float* wx     = (const float*)d_in[5];
    const float* bxp    = (const float*)d_in[6];
    const float* Wh     = (const float*)d_in[7];
    const float* bh     = (const float*)d_in[8];
    const float* W_ih   = (const float*)d_in[9];
    const float* W_hh   = (const float*)d_in[10];
    const float* b_ih   = (const float*)d_in[11];
    const float* b_hh   = (const float*)d_in[12];

    char* wsb   = (char*)d_ws;
    u16*  gamma = (u16*)(wsb + OFF_GAMMA);
    u16*  xrep  = (u16*)(wsb + OFF_XREP);
    u16*  mbf   = (u16*)(wsb + OFF_MBF);
    u16*  wfrag = (u16*)(wsb + OFF_WFRAG);
    float* biasc = (float*)(wsb + OFF_BIASC);
    int*  bar   = (int*)(wsb + OFF_BAR);
    float* hs    = (float*)d_out;
    float* hlast = hs + (size_t)Bb * Tt * Hh;

    k_zero<<<2, 256, 0, stream>>>(bar, 512);
    k_prep<<<(Bb * Tt * Ff / 4) / 256, 256, 0, stream>>>(values, masks, deltas, locf,
                                                         emean, wx, bxp, xrep, mbf);
    k_gamma<<<dim3((Tt * Bb) / 64, Hh / 64), 256, 0, stream>>>(deltas, Wh, bh, gamma);
    k_wcomb<<<(NC * KTOT / 8) / 256, 256, 0, stream>>>(W_ih, W_hh, b_ih, b_hh, wfrag, biasc);

    k_scan<<<dim3(16, 16), 256, 0, stream>>>(xrep, mbf, gamma, wfrag, biasc,
                                             bar, hs, hlast);
}

// Round 5
// 1924.077 us; speedup vs baseline: 2.0088x; 1.0019x over previous
//
#include <hip/hip_runtime.h>
#include <math.h>

#define Bb 256
#define Tt 256
#define Ff 128
#define Hh 512
#define KTOT 768   // 2F+H
#define NC 2048    // 4*H  (gate cols: colH*4 + {r,z,i_n,h_n})

typedef unsigned short u16;
typedef unsigned int   u32;
typedef unsigned long long u64;
typedef __attribute__((ext_vector_type(8))) short s8v;   // 8 bf16 (4 VGPRs)
typedef __attribute__((ext_vector_type(4))) float f4v;   // 4 fp32 acc

// ---------------- ws layout (bytes) ----------------
// gamma  : u16 [Tt*Bb*Hh]        = 67,108,864 B   [T,B,H]
// xrep   : u16 [Bb*Tt*Ff]        = 16,777,216 B
// mbf    : u16 [Bb*Tt*Ff]        = 16,777,216 B
// wfrag  : u16 [NC*KTOT]         =  3,145,728 B   frag-major
// biasc  : f32 [NC]              =      8,192 B
// bar    : i32 [16*32]           =      2,048 B   per-by-group counters (128B apart)
// total ≈ 103.8 MB
#define OFF_GAMMA 0ull
#define OFF_XREP  (OFF_GAMMA + 67108864ull)
#define OFF_MBF   (OFF_XREP  + 16777216ull)
#define OFF_WFRAG (OFF_MBF   + 16777216ull)
#define OFF_BIASC (OFF_WFRAG + 3145728ull)
#define OFF_BAR   (OFF_BIASC + 8192ull)

__device__ __forceinline__ u16 f2b(float x) {   // fp32 -> bf16 RNE
    u32 u = __float_as_uint(x);
    return (u16)((u + 0x7FFFu + ((u >> 16) & 1u)) >> 16);
}
__device__ __forceinline__ float b2f(u16 b) {
    return __uint_as_float(((u32)b) << 16);
}

__global__ __launch_bounds__(256) void k_zero(int* p, int n) {
    int i = blockIdx.x * 256 + threadIdx.x;
    if (i < n) p[i] = 0;
}

__device__ __forceinline__ float xrep_one(float x, float m, float d, float l,
                                          float w, float bb, float em) {
    float gx = expf(-fmaxf(d * w + bb, 0.f));
    float xh = gx * l + (1.f - gx) * em;
    return m * x + (1.f - m) * xh;
}

// Elementwise precompute: x_rep and m in bf16, layout [B][T][F].
__global__ __launch_bounds__(256) void k_prep(const float* __restrict__ values,
                                              const float* __restrict__ masks,
                                              const float* __restrict__ deltas,
                                              const float* __restrict__ locf,
                                              const float* __restrict__ emean,
                                              const float* __restrict__ wx,
                                              const float* __restrict__ bxp,
                                              u16* __restrict__ xrep,
                                              u16* __restrict__ mbf) {
    int idx = blockIdx.x * 256 + threadIdx.x;   // < B*T*F/4
    int e = idx * 4;
    int f = e & 127;
    float4 xv = *(const float4*)&values[e];
    float4 mv = *(const float4*)&masks[e];
    float4 dv = *(const float4*)&deltas[e];
    float4 lv = *(const float4*)&locf[e];
    float4 wv = *(const float4*)&wx[f];
    float4 bv = *(const float4*)&bxp[f];
    float4 ev = *(const float4*)&emean[f];
    u16 o[4], mo[4];
    o[0] = f2b(xrep_one(xv.x, mv.x, dv.x, lv.x, wv.x, bv.x, ev.x));
    o[1] = f2b(xrep_one(xv.y, mv.y, dv.y, lv.y, wv.y, bv.y, ev.y));
    o[2] = f2b(xrep_one(xv.z, mv.z, dv.z, lv.z, wv.z, bv.z, ev.z));
    o[3] = f2b(xrep_one(xv.w, mv.w, dv.w, lv.w, wv.w, bv.w, ev.w));
    mo[0] = f2b(mv.x); mo[1] = f2b(mv.y); mo[2] = f2b(mv.z); mo[3] = f2b(mv.w);
    *(uint2*)&xrep[e] = *(uint2*)o;
    *(uint2*)&mbf[e]  = *(uint2*)mo;
}

// Combined weight, frag-major bf16 (unchanged).
__global__ __launch_bounds__(256) void k_wcomb(const float* __restrict__ W_ih,
                                               const float* __restrict__ W_hh,
                                               const float* __restrict__ b_ih,
                                               const float* __restrict__ b_hh,
                                               u16* __restrict__ wfrag,
                                               float* __restrict__ biasc) {
    int G = blockIdx.x * 256 + threadIdx.x;   // < NC*KTOT/8 = 196608
    int lane = G & 63;
    int q = G >> 6;
    int ki = q % 24; q /= 24;
    int nt = q & 1;  q >>= 1;
    int wv = q & 3;  q >>= 2;
    int bx = q;                                // 0..15
    int c = bx * 128 + wv * 32 + nt * 16 + (lane & 15);
    int kbase = ki * 32 + (lane >> 4) * 8;
    int g = c & 3, jH = c >> 2;
    u16 o[8];
#pragma unroll
    for (int j = 0; j < 8; ++j) {
        int k = kbase + j;
        float w;
        if (g < 3) {
            w = W_ih[(size_t)(g * Hh + jH) * KTOT + k];
            if (g < 2 && k >= Ff && k < Ff + Hh) w += W_hh[(size_t)(g * Hh + jH) * Hh + (k - Ff)];
        } else {
            w = (k >= Ff && k < Ff + Hh) ? W_hh[(size_t)(2 * Hh + jH) * Hh + (k - Ff)] : 0.f;
        }
        o[j] = f2b(w);
    }
    *(uint4*)&wfrag[(size_t)G * 8] = *(uint4*)o;
    if (ki == 0 && (lane >> 4) == 0) {
        float bv;
        if (g == 0)      bv = b_ih[jH] + b_hh[jH];
        else if (g == 1) bv = b_ih[Hh + jH] + b_hh[Hh + jH];
        else if (g == 2) bv = b_ih[2 * Hh + jH];
        else             bv = b_hh[2 * Hh + jH];
        biasc[c] = bv;
    }
}

// gamma_h precompute (fp32 compute, bf16 store): [T*B rows] x [H cols], K=128.
__global__ __launch_bounds__(256) void k_gamma(const float* __restrict__ deltas,
                                               const float* __restrict__ Wh,
                                               const float* __restrict__ bh,
                                               u16* __restrict__ gamma) {
    __shared__ float A_s[64][68];
    __shared__ float B_s[64][68];
    int tid = threadIdx.x;
    int tx = tid & 15, ty = tid >> 4;
    int bt0 = blockIdx.x * 64;
    int c0  = blockIdx.y * 64;

    float acc[4][4];
#pragma unroll
    for (int i = 0; i < 4; ++i)
#pragma unroll
        for (int j = 0; j < 4; ++j) acc[i][j] = 0.f;

    for (int kc = 0; kc < 2; ++kc) {
#pragma unroll
        for (int s = 0; s < 4; ++s) {
            int v = tid + s * 256;
            int row = v >> 4, c4 = v & 15, kk = c4 * 4;
            int bt = bt0 + row;
            int b = bt & 255, tt = bt >> 8;
            float4 a = *(const float4*)&deltas[b * (Tt * Ff) + tt * Ff + kc * 64 + kk];
            *(float4*)&A_s[row][kk] = a;
        }
#pragma unroll
        for (int s = 0; s < 4; ++s) {
            int v = tid + s * 256;
            int col = v >> 4, c4 = v & 15, kk = c4 * 4;
            float4 w = *(const float4*)&Wh[(c0 + col) * Ff + kc * 64 + kk];
            *(float4*)&B_s[col][kk] = w;
        }
        __syncthreads();
#pragma unroll
        for (int kk = 0; kk < 64; kk += 4) {
            float4 a[4], b[4];
#pragma unroll
            for (int i = 0; i < 4; ++i) a[i] = *(const float4*)&A_s[4 * ty + i][kk];
#pragma unroll
            for (int j = 0; j < 4; ++j) b[j] = *(const float4*)&B_s[4 * tx + j][kk];
#pragma unroll
            for (int i = 0; i < 4; ++i)
#pragma unroll
                for (int j = 0; j < 4; ++j) {
                    acc[i][j] += a[i].x * b[j].x;
                    acc[i][j] += a[i].y * b[j].y;
                    acc[i][j] += a[i].z * b[j].z;
                    acc[i][j] += a[i].w * b[j].w;
                }
        }
        __syncthreads();
    }
#pragma unroll
    for (int i = 0; i < 4; ++i) {
        int bt = bt0 + 4 * ty + i;
        u16 o[4];
#pragma unroll
        for (int j = 0; j < 4; ++j) {
            int col = c0 + 4 * tx + j;
            float x = acc[i][j] + bh[col];
            o[j] = f2b(expf(-fmaxf(x, 0.f)));
        }
        *(uint2*)&gamma[(size_t)bt * Hh + c0 + 4 * tx] = *(uint2*)o;
    }
}

// ---------------------------------------------------------------------------
// Persistent scan kernel, v4b (re-run of v4; round-4 failure was infra):
// - XCD-local by-groups: by=(L&7)+8*(L>>7), bx=(L>>3)&15 (bijective). Under
//   round-robin dispatch all 16 blocks of a by-group share one XCD -> the
//   per-step gamma/hs/x/m slabs are fetched once per XCD-L2, not 8x.
//   Pure perf heuristic; correctness is mapping-independent (MALL RMW).
// - h published via atomic-swap into hs (executes at MALL; vmcnt-ack ==
//   visible); consumers read virgin hs addresses (guaranteed miss -> MALL).
// - Spin probe fetch_add(c,0); escape bound 1<<22 (seconds, not minutes).
// ---------------------------------------------------------------------------
__global__ __launch_bounds__(256, 1) void k_scan(const u16* __restrict__ xrep,
                                                 const u16* __restrict__ mbf,
                                                 const u16* __restrict__ gamma,
                                                 const u16* __restrict__ wfrag,
                                                 const float* __restrict__ biasc,
                                                 int* __restrict__ bar,
                                                 float* __restrict__ hs,
                                                 float* __restrict__ hlast) {
    __shared__ u16  A_s[24 * 64 * 8];   // 24.6 KB, frag-major A tile
    __shared__ float E_s[16][132];      // 8.45 KB, gate preacts

    int tid = threadIdx.x;
    int lane = tid & 63, w = tid >> 6;

    // ---- XCD-local swizzle ----
    int L = blockIdx.x + 16 * blockIdx.y;
    int by = (L & 7) + 8 * (L >> 7);        // group -> one XCD (heuristic)
    int bx = (L >> 3) & 15;
    int r0 = by * 16;

    // ---- B fragments ----
    uint4 Bf[2][24];
    const uint4* wf4 = (const uint4*)wfrag;
#pragma unroll
    for (int nt = 0; nt < 2; ++nt)
#pragma unroll
        for (int ki = 0; ki < 24; ++ki)
            Bf[nt][ki] = wf4[(size_t)((((bx * 4 + w) * 2 + nt) * 24 + ki) * 64 + lane)];

    // staging geometry: G = tid + s*256, ki = s*4 + w (wave-uniform),
    // row = lane&15, kbase = ki*32 + (lane>>4)*8.
    int srow = lane & 15;
    int koff = (lane >> 4) * 8;

    // ---- fixed epilogue mapping per thread: row bl, h-cols JH0, JH0+1 ----
    int bl = tid >> 4, jh0 = (tid & 15) * 2;
    int eb = r0 + bl;
    int JH0 = bx * 32 + jh0;
    float hreg0 = 0.f, hreg1 = 0.f;   // decayed h = h(t-1)*gamma_t, f32 (h0 = 0)

    // ---- prologue: stage A tile for t=0 (h region = 0) ----
    {
        int kb = w * 32 + koff;
        *(uint4*)&A_s[tid * 8] =
            *(const uint4*)&xrep[(size_t)(r0 + srow) * (Tt * Ff) + 0 * Ff + kb];
        *(uint4*)&A_s[(tid + 5 * 256) * 8] =
            *(const uint4*)&mbf[(size_t)(r0 + srow) * (Tt * Ff) + 0 * Ff + kb];
        uint4 z; z.x = 0; z.y = 0; z.z = 0; z.w = 0;
#pragma unroll
        for (int s = 1; s <= 4; ++s)
            *(uint4*)&A_s[(tid + s * 256) * 8] = z;
    }
    __syncthreads();

    for (int t = 0; t < Tt; ++t) {
        // ---- MFMA: 24 k-iters x 2 N-tiles ----
        f4v acc0 = {0.f, 0.f, 0.f, 0.f};
        f4v acc1 = {0.f, 0.f, 0.f, 0.f};
#pragma unroll
        for (int ki = 0; ki < 24; ++ki) {
            s8v a = *(const s8v*)&A_s[(ki * 64 + lane) * 8];
            acc0 = __builtin_amdgcn_mfma_f32_16x16x32_bf16(a, __builtin_bit_cast(s8v, Bf[0][ki]), acc0, 0, 0, 0);
            acc1 = __builtin_amdgcn_mfma_f32_16x16x32_bf16(a, __builtin_bit_cast(s8v, Bf[1][ki]), acc1, 0, 0, 0);
        }

        // ---- C layout (row=(lane>>4)*4+reg, col=lane&15) -> LDS ----
        {
            int colb = w * 32 + (lane & 15);
            int rq = (lane >> 4) * 4;
#pragma unroll
            for (int r = 0; r < 4; ++r) {
                E_s[rq + r][colb]      = acc0[r];
                E_s[rq + r][colb + 16] = acc1[r];
            }
        }
        __syncthreads();   // E_s ready; A_s free (all MFMA reads done)

        // ---- barrier-independent prefetch for t+1: x/m -> A_s, gamma -> regs ----
        uint4 g4[4];
        if (t < Tt - 1) {
            int kb = w * 32 + koff;
            *(uint4*)&A_s[tid * 8] =
                *(const uint4*)&xrep[(size_t)(r0 + srow) * (Tt * Ff) + (t + 1) * Ff + kb];
            *(uint4*)&A_s[(tid + 5 * 256) * 8] =
                *(const uint4*)&mbf[(size_t)(r0 + srow) * (Tt * Ff) + (t + 1) * Ff + kb];
#pragma unroll
            for (int s = 1; s <= 4; ++s) {
                int kh = (s * 4 + w) * 32 + koff - 128;   // 0..511
                g4[s - 1] = *(const uint4*)&gamma[((size_t)(t + 1) * Bb + (r0 + srow)) * Hh + kh];
            }
        }

        // ---- gates + h update: 2 consecutive h-cols per thread ----
        float4 p0  = *(const float4*)&E_s[bl][jh0 * 4];
        float4 p1  = *(const float4*)&E_s[bl][jh0 * 4 + 4];
        float4 bi0 = *(const float4*)&biasc[JH0 * 4];
        float4 bi1 = *(const float4*)&biasc[JH0 * 4 + 4];
        float rg0 = 1.f / (1.f + expf(-(p0.x + bi0.x)));
        float zz0 = 1.f / (1.f + expf(-(p0.y + bi0.y)));
        float nn0 = tanhf(p0.z + bi0.z + rg0 * (p0.w + bi0.w));
        float hn0 = (1.f - zz0) * nn0 + zz0 * hreg0;
        float rg1 = 1.f / (1.f + expf(-(p1.x + bi1.x)));
        float zz1 = 1.f / (1.f + expf(-(p1.y + bi1.y)));
        float nn1 = tanhf(p1.z + bi1.z + rg1 * (p1.w + bi1.w));
        float hn1 = (1.f - zz1) * nn1 + zz1 * hreg1;

        // publish h_t via RMW (executes at MALL; doubles as the output store)
        union { float f[2]; u64 u; } pk;
        pk.f[0] = hn0; pk.f[1] = hn1;
        __hip_atomic_exchange((u64*)&hs[(size_t)eb * (Tt * Hh) + (size_t)t * Hh + JH0],
                              pk.u, __ATOMIC_RELAXED, __HIP_MEMORY_SCOPE_AGENT);

        if (t < Tt - 1) {
            // decay for next step: f32 in regs (epilogue path)
            u32 g = *(const u32*)&gamma[((size_t)(t + 1) * Bb + eb) * Hh + JH0];
            hreg0 = hn0 * b2f((u16)(g & 0xffffu));
            hreg1 = hn1 * b2f((u16)(g >> 16));

            // ---- group barrier: all swaps drained, then RMW counter ----
            asm volatile("s_waitcnt vmcnt(0)" ::: "memory");
            __syncthreads();
            if (tid == 0) {
                int* c = &bar[by * 32];
                __hip_atomic_fetch_add(c, 1, __ATOMIC_RELAXED, __HIP_MEMORY_SCOPE_AGENT);
                int target = 16 * (t + 1);
                int iters = 0;
                while (__hip_atomic_fetch_add(c, 0, __ATOMIC_RELAXED,
                                              __HIP_MEMORY_SCOPE_AGENT) < target) {
                    __builtin_amdgcn_s_sleep(1);
                    if (++iters > (1 << 22)) break;   // visible-failure escape
                }
            }
            __syncthreads();

            // ---- stage t+1 h region: batch-issue loads, then convert ----
            float4 hb[8];
#pragma unroll
            for (int s = 1; s <= 4; ++s) {
                int kh = (s * 4 + w) * 32 + koff - 128;   // 0..511
                const float* hp = &hs[(size_t)(r0 + srow) * (Tt * Hh) + (size_t)t * Hh + kh];
                hb[2 * (s - 1)]     = *(const float4*)hp;
                hb[2 * (s - 1) + 1] = *(const float4*)(hp + 4);
            }
#pragma unroll
            for (int s = 1; s <= 4; ++s) {
                float4 h0 = hb[2 * (s - 1)];
                float4 h1 = hb[2 * (s - 1) + 1];
                u16 g8[8];
                *(uint4*)g8 = g4[s - 1];
                u16 o[8];
                o[0] = f2b(h0.x * b2f(g8[0])); o[1] = f2b(h0.y * b2f(g8[1]));
                o[2] = f2b(h0.z * b2f(g8[2])); o[3] = f2b(h0.w * b2f(g8[3]));
                o[4] = f2b(h1.x * b2f(g8[4])); o[5] = f2b(h1.y * b2f(g8[5]));
                o[6] = f2b(h1.z * b2f(g8[6])); o[7] = f2b(h1.w * b2f(g8[7]));
                *(uint4*)&A_s[(tid + s * 256) * 8] = *(uint4*)o;
            }
            __syncthreads();
        } else {
            float2 hn2; hn2.x = hn0; hn2.y = hn1;
            *(float2*)&hlast[eb * Hh + JH0] = hn2;
        }
    }
}

extern "C" void kernel_launch(void* const* d_in, const int* in_sizes, int n_in,
                              void* d_out, int out_size, void* d_ws, size_t ws_size,
                              hipStream_t stream) {
    const float* values = (const float*)d_in[0];
    const float* masks  = (const float*)d_in[1];
    const float* deltas = (const float*)d_in[2];
    const float* emean  = (const float*)d_in[3];
    const float* locf   = (const float*)d_in[4];
    const float* wx     = (const float*)d_in[5];
    const float* bxp    = (const float*)d_in[6];
    const float* Wh     = (const float*)d_in[7];
    const float* bh     = (const float*)d_in[8];
    const float* W_ih   = (const float*)d_in[9];
    const float* W_hh   = (const float*)d_in[10];
    const float* b_ih   = (const float*)d_in[11];
    const float* b_hh   = (const float*)d_in[12];

    char* wsb   = (char*)d_ws;
    u16*  gamma = (u16*)(wsb + OFF_GAMMA);
    u16*  xrep  = (u16*)(wsb + OFF_XREP);
    u16*  mbf   = (u16*)(wsb + OFF_MBF);
    u16*  wfrag = (u16*)(wsb + OFF_WFRAG);
    float* biasc = (float*)(wsb + OFF_BIASC);
    int*  bar   = (int*)(wsb + OFF_BAR);
    float* hs    = (float*)d_out;
    float* hlast = hs + (size_t)Bb * Tt * Hh;

    k_zero<<<2, 256, 0, stream>>>(bar, 512);
    k_prep<<<(Bb * Tt * Ff / 4) / 256, 256, 0, stream>>>(values, masks, deltas, locf,
                                                         emean, wx, bxp, xrep, mbf);
    k_gamma<<<dim3((Tt * Bb) / 64, Hh / 64), 256, 0, stream>>>(deltas, Wh, bh, gamma);
    k_wcomb<<<(NC * KTOT / 8) / 256, 256, 0, stream>>>(W_ih, W_hh, b_ih, b_hh, wfrag, biasc);

    k_scan<<<dim3(16, 16), 256, 0, stream>>>(xrep, mbf, gamma, wfrag, biasc,
                                             bar, hs, hlast);
}

// Round 6
// 1684.724 us; speedup vs baseline: 2.2942x; 1.1421x over previous
//
#include <hip/hip_runtime.h>
#include <math.h>

#define Bb 256
#define Tt 256
#define Ff 128
#define Hh 512
#define KTOT 768   // 2F+H
#define NC 2048    // 4*H  (gate cols: colH*4 + {r,z,i_n,h_n})

typedef unsigned short u16;
typedef unsigned int   u32;
typedef unsigned long long u64;
typedef __attribute__((ext_vector_type(8))) short s8v;   // 8 bf16 (4 VGPRs)
typedef __attribute__((ext_vector_type(4))) float f4v;   // 4 fp32 acc

// ---------------- ws layout (bytes) ----------------
// gamma  : u16 [Tt*Bb*Hh]        = 67,108,864 B   [T,B,H]
// xrep   : u16 [Bb*Tt*Ff]        = 16,777,216 B
// mbf    : u16 [Bb*Tt*Ff]        = 16,777,216 B
// wfrag  : u16 [NC*KTOT]         =  3,145,728 B   frag-major
// biasc  : f32 [NC]              =      8,192 B
// bar    : i32 [16*32]           =      2,048 B   per-by-group counters (128B apart)
// total ≈ 103.8 MB
#define OFF_GAMMA 0ull
#define OFF_XREP  (OFF_GAMMA + 67108864ull)
#define OFF_MBF   (OFF_XREP  + 16777216ull)
#define OFF_WFRAG (OFF_MBF   + 16777216ull)
#define OFF_BIASC (OFF_WFRAG + 3145728ull)
#define OFF_BAR   (OFF_BIASC + 8192ull)

__device__ __forceinline__ u16 f2b(float x) {   // fp32 -> bf16 RNE
    u32 u = __float_as_uint(x);
    return (u16)((u + 0x7FFFu + ((u >> 16) & 1u)) >> 16);
}
__device__ __forceinline__ float b2f(u16 b) {
    return __uint_as_float(((u32)b) << 16);
}

__global__ __launch_bounds__(256) void k_zero(int* p, int n) {
    int i = blockIdx.x * 256 + threadIdx.x;
    if (i < n) p[i] = 0;
}

__device__ __forceinline__ float xrep_one(float x, float m, float d, float l,
                                          float w, float bb, float em) {
    float gx = expf(-fmaxf(d * w + bb, 0.f));
    float xh = gx * l + (1.f - gx) * em;
    return m * x + (1.f - m) * xh;
}

// Elementwise precompute: x_rep and m in bf16, layout [B][T][F].
__global__ __launch_bounds__(256) void k_prep(const float* __restrict__ values,
                                              const float* __restrict__ masks,
                                              const float* __restrict__ deltas,
                                              const float* __restrict__ locf,
                                              const float* __restrict__ emean,
                                              const float* __restrict__ wx,
                                              const float* __restrict__ bxp,
                                              u16* __restrict__ xrep,
                                              u16* __restrict__ mbf) {
    int idx = blockIdx.x * 256 + threadIdx.x;   // < B*T*F/4
    int e = idx * 4;
    int f = e & 127;
    float4 xv = *(const float4*)&values[e];
    float4 mv = *(const float4*)&masks[e];
    float4 dv = *(const float4*)&deltas[e];
    float4 lv = *(const float4*)&locf[e];
    float4 wv = *(const float4*)&wx[f];
    float4 bv = *(const float4*)&bxp[f];
    float4 ev = *(const float4*)&emean[f];
    u16 o[4], mo[4];
    o[0] = f2b(xrep_one(xv.x, mv.x, dv.x, lv.x, wv.x, bv.x, ev.x));
    o[1] = f2b(xrep_one(xv.y, mv.y, dv.y, lv.y, wv.y, bv.y, ev.y));
    o[2] = f2b(xrep_one(xv.z, mv.z, dv.z, lv.z, wv.z, bv.z, ev.z));
    o[3] = f2b(xrep_one(xv.w, mv.w, dv.w, lv.w, wv.w, bv.w, ev.w));
    mo[0] = f2b(mv.x); mo[1] = f2b(mv.y); mo[2] = f2b(mv.z); mo[3] = f2b(mv.w);
    *(uint2*)&xrep[e] = *(uint2*)o;
    *(uint2*)&mbf[e]  = *(uint2*)mo;
}

// Combined weight, frag-major bf16 (unchanged).
__global__ __launch_bounds__(256) void k_wcomb(const float* __restrict__ W_ih,
                                               const float* __restrict__ W_hh,
                                               const float* __restrict__ b_ih,
                                               const float* __restrict__ b_hh,
                                               u16* __restrict__ wfrag,
                                               float* __restrict__ biasc) {
    int G = blockIdx.x * 256 + threadIdx.x;   // < NC*KTOT/8 = 196608
    int lane = G & 63;
    int q = G >> 6;
    int ki = q % 24; q /= 24;
    int nt = q & 1;  q >>= 1;
    int wv = q & 3;  q >>= 2;
    int bx = q;                                // 0..15
    int c = bx * 128 + wv * 32 + nt * 16 + (lane & 15);
    int kbase = ki * 32 + (lane >> 4) * 8;
    int g = c & 3, jH = c >> 2;
    u16 o[8];
#pragma unroll
    for (int j = 0; j < 8; ++j) {
        int k = kbase + j;
        float w;
        if (g < 3) {
            w = W_ih[(size_t)(g * Hh + jH) * KTOT + k];
            if (g < 2 && k >= Ff && k < Ff + Hh) w += W_hh[(size_t)(g * Hh + jH) * Hh + (k - Ff)];
        } else {
            w = (k >= Ff && k < Ff + Hh) ? W_hh[(size_t)(2 * Hh + jH) * Hh + (k - Ff)] : 0.f;
        }
        o[j] = f2b(w);
    }
    *(uint4*)&wfrag[(size_t)G * 8] = *(uint4*)o;
    if (ki == 0 && (lane >> 4) == 0) {
        float bv;
        if (g == 0)      bv = b_ih[jH] + b_hh[jH];
        else if (g == 1) bv = b_ih[Hh + jH] + b_hh[Hh + jH];
        else if (g == 2) bv = b_ih[2 * Hh + jH];
        else             bv = b_hh[2 * Hh + jH];
        biasc[c] = bv;
    }
}

// gamma_h precompute (fp32 compute, bf16 store): [T*B rows] x [H cols], K=128.
__global__ __launch_bounds__(256) void k_gamma(const float* __restrict__ deltas,
                                               const float* __restrict__ Wh,
                                               const float* __restrict__ bh,
                                               u16* __restrict__ gamma) {
    __shared__ float A_s[64][68];
    __shared__ float B_s[64][68];
    int tid = threadIdx.x;
    int tx = tid & 15, ty = tid >> 4;
    int bt0 = blockIdx.x * 64;
    int c0  = blockIdx.y * 64;

    float acc[4][4];
#pragma unroll
    for (int i = 0; i < 4; ++i)
#pragma unroll
        for (int j = 0; j < 4; ++j) acc[i][j] = 0.f;

    for (int kc = 0; kc < 2; ++kc) {
#pragma unroll
        for (int s = 0; s < 4; ++s) {
            int v = tid + s * 256;
            int row = v >> 4, c4 = v & 15, kk = c4 * 4;
            int bt = bt0 + row;
            int b = bt & 255, tt = bt >> 8;
            float4 a = *(const float4*)&deltas[b * (Tt * Ff) + tt * Ff + kc * 64 + kk];
            *(float4*)&A_s[row][kk] = a;
        }
#pragma unroll
        for (int s = 0; s < 4; ++s) {
            int v = tid + s * 256;
            int col = v >> 4, c4 = v & 15, kk = c4 * 4;
            float4 w = *(const float4*)&Wh[(c0 + col) * Ff + kc * 64 + kk];
            *(float4*)&B_s[col][kk] = w;
        }
        __syncthreads();
#pragma unroll
        for (int kk = 0; kk < 64; kk += 4) {
            float4 a[4], b[4];
#pragma unroll
            for (int i = 0; i < 4; ++i) a[i] = *(const float4*)&A_s[4 * ty + i][kk];
#pragma unroll
            for (int j = 0; j < 4; ++j) b[j] = *(const float4*)&B_s[4 * tx + j][kk];
#pragma unroll
            for (int i = 0; i < 4; ++i)
#pragma unroll
                for (int j = 0; j < 4; ++j) {
                    acc[i][j] += a[i].x * b[j].x;
                    acc[i][j] += a[i].y * b[j].y;
                    acc[i][j] += a[i].z * b[j].z;
                    acc[i][j] += a[i].w * b[j].w;
                }
        }
        __syncthreads();
    }
#pragma unroll
    for (int i = 0; i < 4; ++i) {
        int bt = bt0 + 4 * ty + i;
        u16 o[4];
#pragma unroll
        for (int j = 0; j < 4; ++j) {
            int col = c0 + 4 * tx + j;
            float x = acc[i][j] + bh[col];
            o[j] = f2b(expf(-fmaxf(x, 0.f)));
        }
        *(uint2*)&gamma[(size_t)bt * Hh + c0 + 4 * tx] = *(uint2*)o;
    }
}

// ---------------------------------------------------------------------------
// Persistent scan kernel, v5: 512 threads / 8 waves per block, 1 N-tile/wave.
// - Wave w owns 16 gate cols -> Bf[24] = 96 VGPRs, genuinely register-resident
//   (v4b's Bf[2][24]=192 > VGPR_Count=136 proved re-loads from L2 every step).
// - 8 waves/CU (2/SIMD) doubles latency hiding; MFMA chain halves (24/wave);
//   epilogue is 1 colH/thread (transcendental work halves).
// - Same XCD-local by-group swizzle, same MALL-RMW exchange + counter barrier
//   as the passing v4b (mapping-independent correctness).
// ---------------------------------------------------------------------------
__global__ __launch_bounds__(512, 2) void k_scan(const u16* __restrict__ xrep,
                                                 const u16* __restrict__ mbf,
                                                 const u16* __restrict__ gamma,
                                                 const u16* __restrict__ wfrag,
                                                 const float* __restrict__ biasc,
                                                 int* __restrict__ bar,
                                                 float* __restrict__ hs,
                                                 float* __restrict__ hlast) {
    __shared__ u16  A_s[24 * 64 * 8];   // 24.6 KB, frag-major A tile
    __shared__ float E_s[16][132];      // 8.45 KB, gate preacts

    int tid = threadIdx.x;
    int lane = tid & 63, w = tid >> 6;   // 8 waves

    // ---- XCD-local swizzle (bijective; by-group -> one XCD heuristic) ----
    int L = blockIdx.x + 16 * blockIdx.y;
    int by = (L & 7) + 8 * (L >> 7);
    int bx = (L >> 3) & 15;
    int r0 = by * 16;

    // ---- B fragments: wave w owns cols bx*128 + w*16 + (lane&15); resident ----
    uint4 Bf[24];
    const uint4* wf4 = (const uint4*)wfrag;
#pragma unroll
    for (int ki = 0; ki < 24; ++ki)
        Bf[ki] = wf4[(size_t)(((bx * 8 + w) * 24 + ki) * 64 + lane)];

    // staging geometry: frag entry (ki, slot=lane): row = lane&15,
    // kbase = ki*32 + (lane>>4)*8. Waves 0..3 stage x (ki=w), 4..7 stage m
    // (ki=16+w); h entries (ki 4..19) = 2 per thread post-barrier.
    int srow = lane & 15;
    int koff = (lane >> 4) * 8;

    // ---- fixed epilogue mapping: one (row, colH) per thread ----
    int bl = tid >> 5, jh = tid & 31;    // row 0..15, colH 0..31
    int eb = r0 + bl;
    int JH = bx * 32 + jh;
    float4 bi = *(const float4*)&biasc[JH * 4];   // loop-invariant
    float hreg = 0.f;                    // decayed h = h(t-1)*gamma_t (h0 = 0)

    // ---- prologue: stage A tile for t=0 (h region = 0) ----
    {
        if (w < 4) {
            int kb = w * 32 + koff;
            *(uint4*)&A_s[tid * 8] =
                *(const uint4*)&xrep[(size_t)(r0 + srow) * (Tt * Ff) + 0 * Ff + kb];
        } else {
            int kb = (w - 4) * 32 + koff;
            *(uint4*)&A_s[(tid + 1024) * 8] =
                *(const uint4*)&mbf[(size_t)(r0 + srow) * (Tt * Ff) + 0 * Ff + kb];
        }
        uint4 z; z.x = 0; z.y = 0; z.z = 0; z.w = 0;
#pragma unroll
        for (int e = 0; e < 2; ++e) {
            int ki = 4 + 8 * e + w;
            *(uint4*)&A_s[(ki * 64 + lane) * 8] = z;
        }
    }
    __syncthreads();

    for (int t = 0; t < Tt; ++t) {
        // ---- MFMA: 24 k-iters, 1 N-tile per wave ----
        f4v acc = {0.f, 0.f, 0.f, 0.f};
#pragma unroll
        for (int ki = 0; ki < 24; ++ki) {
            s8v a = *(const s8v*)&A_s[(ki * 64 + lane) * 8];
            acc = __builtin_amdgcn_mfma_f32_16x16x32_bf16(a, __builtin_bit_cast(s8v, Bf[ki]), acc, 0, 0, 0);
        }

        // ---- C layout (row=(lane>>4)*4+reg, col=lane&15) -> LDS ----
        {
            int colb = w * 16 + (lane & 15);
            int rq = (lane >> 4) * 4;
#pragma unroll
            for (int r = 0; r < 4; ++r)
                E_s[rq + r][colb] = acc[r];
        }
        __syncthreads();   // E_s ready; A_s free (all MFMA reads done)

        // ---- barrier-independent prefetch for t+1 ----
        uint4 g4[2];       // gamma for the 2 h frag-entries this thread stages
        u16 gdec = 0;      // gamma for this thread's epilogue decay
        if (t < Tt - 1) {
            if (w < 4) {
                int kb = w * 32 + koff;
                *(uint4*)&A_s[tid * 8] =
                    *(const uint4*)&xrep[(size_t)(r0 + srow) * (Tt * Ff) + (t + 1) * Ff + kb];
            } else {
                int kb = (w - 4) * 32 + koff;
                *(uint4*)&A_s[(tid + 1024) * 8] =
                    *(const uint4*)&mbf[(size_t)(r0 + srow) * (Tt * Ff) + (t + 1) * Ff + kb];
            }
#pragma unroll
            for (int e = 0; e < 2; ++e) {
                int ki = 4 + 8 * e + w;
                int kh = (ki - 4) * 32 + koff;   // 0..511
                g4[e] = *(const uint4*)&gamma[((size_t)(t + 1) * Bb + (r0 + srow)) * Hh + kh];
            }
            gdec = gamma[((size_t)(t + 1) * Bb + eb) * Hh + JH];
        }

        // ---- gates + h update: ONE (row, colH) per thread ----
        float4 p = *(const float4*)&E_s[bl][jh * 4];
        float rg = 1.f / (1.f + expf(-(p.x + bi.x)));
        float zz = 1.f / (1.f + expf(-(p.y + bi.y)));
        float nn = tanhf(p.z + bi.z + rg * (p.w + bi.w));
        float hn = (1.f - zz) * nn + zz * hreg;

        // publish h_t via RMW (executes at MALL; doubles as the output store)
        __hip_atomic_exchange((u32*)&hs[(size_t)eb * (Tt * Hh) + (size_t)t * Hh + JH],
                              __float_as_uint(hn), __ATOMIC_RELAXED,
                              __HIP_MEMORY_SCOPE_AGENT);

        if (t < Tt - 1) {
            hreg = hn * b2f(gdec);       // decay for next step (f32 in regs)

            // ---- group barrier: all swaps drained, then RMW counter ----
            asm volatile("s_waitcnt vmcnt(0)" ::: "memory");
            __syncthreads();
            if (tid == 0) {
                int* c = &bar[by * 32];
                __hip_atomic_fetch_add(c, 1, __ATOMIC_RELAXED, __HIP_MEMORY_SCOPE_AGENT);
                int target = 16 * (t + 1);
                int iters = 0;
                while (__hip_atomic_fetch_add(c, 0, __ATOMIC_RELAXED,
                                              __HIP_MEMORY_SCOPE_AGENT) < target) {
                    __builtin_amdgcn_s_sleep(1);
                    if (++iters > (1 << 22)) break;   // visible-failure escape
                }
            }
            __syncthreads();

            // ---- stage t+1 h region: 2 frag-entries/thread, batch loads ----
            float4 hb[4];
#pragma unroll
            for (int e = 0; e < 2; ++e) {
                int ki = 4 + 8 * e + w;
                int kh = (ki - 4) * 32 + koff;   // 0..511
                const float* hp = &hs[(size_t)(r0 + srow) * (Tt * Hh) + (size_t)t * Hh + kh];
                hb[2 * e]     = *(const float4*)hp;
                hb[2 * e + 1] = *(const float4*)(hp + 4);
            }
#pragma unroll
            for (int e = 0; e < 2; ++e) {
                int ki = 4 + 8 * e + w;
                float4 h0 = hb[2 * e];
                float4 h1 = hb[2 * e + 1];
                u16 g8[8];
                *(uint4*)g8 = g4[e];
                u16 o[8];
                o[0] = f2b(h0.x * b2f(g8[0])); o[1] = f2b(h0.y * b2f(g8[1]));
                o[2] = f2b(h0.z * b2f(g8[2])); o[3] = f2b(h0.w * b2f(g8[3]));
                o[4] = f2b(h1.x * b2f(g8[4])); o[5] = f2b(h1.y * b2f(g8[5]));
                o[6] = f2b(h1.z * b2f(g8[6])); o[7] = f2b(h1.w * b2f(g8[7]));
                *(uint4*)&A_s[(ki * 64 + lane) * 8] = *(uint4*)o;
            }
            __syncthreads();
        } else {
            hlast[eb * Hh + JH] = hn;
        }
    }
}

extern "C" void kernel_launch(void* const* d_in, const int* in_sizes, int n_in,
                              void* d_out, int out_size, void* d_ws, size_t ws_size,
                              hipStream_t stream) {
    const float* values = (const float*)d_in[0];
    const float* masks  = (const float*)d_in[1];
    const float* deltas = (const float*)d_in[2];
    const float* emean  = (const float*)d_in[3];
    const float* locf   = (const float*)d_in[4];
    const float* wx     = (const float*)d_in[5];
    const float* bxp    = (const float*)d_in[6];
    const float* Wh     = (const float*)d_in[7];
    const float* bh     = (const float*)d_in[8];
    const float* W_ih   = (const float*)d_in[9];
    const float* W_hh   = (const float*)d_in[10];
    const float* b_ih   = (const float*)d_in[11];
    const float* b_hh   = (const float*)d_in[12];

    char* wsb   = (char*)d_ws;
    u16*  gamma = (u16*)(wsb + OFF_GAMMA);
    u16*  xrep  = (u16*)(wsb + OFF_XREP);
    u16*  mbf   = (u16*)(wsb + OFF_MBF);
    u16*  wfrag = (u16*)(wsb + OFF_WFRAG);
    float* biasc = (float*)(wsb + OFF_BIASC);
    int*  bar   = (int*)(wsb + OFF_BAR);
    float* hs    = (float*)d_out;
    float* hlast = hs + (size_t)Bb * Tt * Hh;

    k_zero<<<2, 256, 0, stream>>>(bar, 512);
    k_prep<<<(Bb * Tt * Ff / 4) / 256, 256, 0, stream>>>(values, masks, deltas, locf,
                                                         emean, wx, bxp, xrep, mbf);
    k_gamma<<<dim3((Tt * Bb) / 64, Hh / 64), 256, 0, stream>>>(deltas, Wh, bh, gamma);
    k_wcomb<<<(NC * KTOT / 8) / 256, 256, 0, stream>>>(W_ih, W_hh, b_ih, b_hh, wfrag, biasc);

    k_scan<<<dim3(16, 16), 512, 0, stream>>>(xrep, mbf, gamma, wfrag, biasc,
                                             bar, hs, hlast);
}

// Round 7
// 1683.057 us; speedup vs baseline: 2.2965x; 1.0010x over previous
//
#include <hip/hip_runtime.h>
#include <math.h>

#define Bb 256
#define Tt 256
#define Ff 128
#define Hh 512
#define KTOT 768   // 2F+H
#define NC 2048    // 4*H  (gate cols: colH*4 + {r,z,i_n,h_n})

typedef unsigned short u16;
typedef unsigned int   u32;
typedef unsigned long long u64;
typedef __attribute__((ext_vector_type(8))) short s8v;   // 8 bf16 (4 VGPRs)
typedef __attribute__((ext_vector_type(4))) float f4v;   // 4 fp32 acc
typedef __attribute__((ext_vector_type(4))) u32  u32x4;  // 4 u32 (4 VGPRs)

// ---------------- ws layout (bytes) ----------------
// gamma  : u16 [Tt*Bb*Hh]        = 67,108,864 B   [T,B,H]
// xrep   : u16 [Bb*Tt*Ff]        = 16,777,216 B
// mbf    : u16 [Bb*Tt*Ff]        = 16,777,216 B
// wfrag  : u16 [NC*KTOT]         =  3,145,728 B   frag-major
// biasc  : f32 [NC]              =      8,192 B
// bar    : i32 [16*32]           =      2,048 B   per-by-group counters (128B apart)
// total ≈ 103.8 MB
#define OFF_GAMMA 0ull
#define OFF_XREP  (OFF_GAMMA + 67108864ull)
#define OFF_MBF   (OFF_XREP  + 16777216ull)
#define OFF_WFRAG (OFF_MBF   + 16777216ull)
#define OFF_BIASC (OFF_WFRAG + 3145728ull)
#define OFF_BAR   (OFF_BIASC + 8192ull)

__device__ __forceinline__ u16 f2b(float x) {   // fp32 -> bf16 RNE
    u32 u = __float_as_uint(x);
    return (u16)((u + 0x7FFFu + ((u >> 16) & 1u)) >> 16);
}
__device__ __forceinline__ float b2f(u16 b) {
    return __uint_as_float(((u32)b) << 16);
}

__global__ __launch_bounds__(256) void k_zero(int* p, int n) {
    int i = blockIdx.x * 256 + threadIdx.x;
    if (i < n) p[i] = 0;
}

__device__ __forceinline__ float xrep_one(float x, float m, float d, float l,
                                          float w, float bb, float em) {
    float gx = expf(-fmaxf(d * w + bb, 0.f));
    float xh = gx * l + (1.f - gx) * em;
    return m * x + (1.f - m) * xh;
}

// Elementwise precompute: x_rep and m in bf16, layout [B][T][F].
__global__ __launch_bounds__(256) void k_prep(const float* __restrict__ values,
                                              const float* __restrict__ masks,
                                              const float* __restrict__ deltas,
                                              const float* __restrict__ locf,
                                              const float* __restrict__ emean,
                                              const float* __restrict__ wx,
                                              const float* __restrict__ bxp,
                                              u16* __restrict__ xrep,
                                              u16* __restrict__ mbf) {
    int idx = blockIdx.x * 256 + threadIdx.x;   // < B*T*F/4
    int e = idx * 4;
    int f = e & 127;
    float4 xv = *(const float4*)&values[e];
    float4 mv = *(const float4*)&masks[e];
    float4 dv = *(const float4*)&deltas[e];
    float4 lv = *(const float4*)&locf[e];
    float4 wv = *(const float4*)&wx[f];
    float4 bv = *(const float4*)&bxp[f];
    float4 ev = *(const float4*)&emean[f];
    u16 o[4], mo[4];
    o[0] = f2b(xrep_one(xv.x, mv.x, dv.x, lv.x, wv.x, bv.x, ev.x));
    o[1] = f2b(xrep_one(xv.y, mv.y, dv.y, lv.y, wv.y, bv.y, ev.y));
    o[2] = f2b(xrep_one(xv.z, mv.z, dv.z, lv.z, wv.z, bv.z, ev.z));
    o[3] = f2b(xrep_one(xv.w, mv.w, dv.w, lv.w, wv.w, bv.w, ev.w));
    mo[0] = f2b(mv.x); mo[1] = f2b(mv.y); mo[2] = f2b(mv.z); mo[3] = f2b(mv.w);
    *(uint2*)&xrep[e] = *(uint2*)o;
    *(uint2*)&mbf[e]  = *(uint2*)mo;
}

// Combined weight, frag-major bf16 (unchanged).
__global__ __launch_bounds__(256) void k_wcomb(const float* __restrict__ W_ih,
                                               const float* __restrict__ W_hh,
                                               const float* __restrict__ b_ih,
                                               const float* __restrict__ b_hh,
                                               u16* __restrict__ wfrag,
                                               float* __restrict__ biasc) {
    int G = blockIdx.x * 256 + threadIdx.x;   // < NC*KTOT/8 = 196608
    int lane = G & 63;
    int q = G >> 6;
    int ki = q % 24; q /= 24;
    int nt = q & 1;  q >>= 1;
    int wv = q & 3;  q >>= 2;
    int bx = q;                                // 0..15
    int c = bx * 128 + wv * 32 + nt * 16 + (lane & 15);
    int kbase = ki * 32 + (lane >> 4) * 8;
    int g = c & 3, jH = c >> 2;
    u16 o[8];
#pragma unroll
    for (int j = 0; j < 8; ++j) {
        int k = kbase + j;
        float w;
        if (g < 3) {
            w = W_ih[(size_t)(g * Hh + jH) * KTOT + k];
            if (g < 2 && k >= Ff && k < Ff + Hh) w += W_hh[(size_t)(g * Hh + jH) * Hh + (k - Ff)];
        } else {
            w = (k >= Ff && k < Ff + Hh) ? W_hh[(size_t)(2 * Hh + jH) * Hh + (k - Ff)] : 0.f;
        }
        o[j] = f2b(w);
    }
    *(uint4*)&wfrag[(size_t)G * 8] = *(uint4*)o;
    if (ki == 0 && (lane >> 4) == 0) {
        float bv;
        if (g == 0)      bv = b_ih[jH] + b_hh[jH];
        else if (g == 1) bv = b_ih[Hh + jH] + b_hh[Hh + jH];
        else if (g == 2) bv = b_ih[2 * Hh + jH];
        else             bv = b_hh[2 * Hh + jH];
        biasc[c] = bv;
    }
}

// gamma_h precompute (fp32 compute, bf16 store): [T*B rows] x [H cols], K=128.
__global__ __launch_bounds__(256) void k_gamma(const float* __restrict__ deltas,
                                               const float* __restrict__ Wh,
                                               const float* __restrict__ bh,
                                               u16* __restrict__ gamma) {
    __shared__ float A_s[64][68];
    __shared__ float B_s[64][68];
    int tid = threadIdx.x;
    int tx = tid & 15, ty = tid >> 4;
    int bt0 = blockIdx.x * 64;
    int c0  = blockIdx.y * 64;

    float acc[4][4];
#pragma unroll
    for (int i = 0; i < 4; ++i)
#pragma unroll
        for (int j = 0; j < 4; ++j) acc[i][j] = 0.f;

    for (int kc = 0; kc < 2; ++kc) {
#pragma unroll
        for (int s = 0; s < 4; ++s) {
            int v = tid + s * 256;
            int row = v >> 4, c4 = v & 15, kk = c4 * 4;
            int bt = bt0 + row;
            int b = bt & 255, tt = bt >> 8;
            float4 a = *(const float4*)&deltas[b * (Tt * Ff) + tt * Ff + kc * 64 + kk];
            *(float4*)&A_s[row][kk] = a;
        }
#pragma unroll
        for (int s = 0; s < 4; ++s) {
            int v = tid + s * 256;
            int col = v >> 4, c4 = v & 15, kk = c4 * 4;
            float4 w = *(const float4*)&Wh[(c0 + col) * Ff + kc * 64 + kk];
            *(float4*)&B_s[col][kk] = w;
        }
        __syncthreads();
#pragma unroll
        for (int kk = 0; kk < 64; kk += 4) {
            float4 a[4], b[4];
#pragma unroll
            for (int i = 0; i < 4; ++i) a[i] = *(const float4*)&A_s[4 * ty + i][kk];
#pragma unroll
            for (int j = 0; j < 4; ++j) b[j] = *(const float4*)&B_s[4 * tx + j][kk];
#pragma unroll
            for (int i = 0; i < 4; ++i)
#pragma unroll
                for (int j = 0; j < 4; ++j) {
                    acc[i][j] += a[i].x * b[j].x;
                    acc[i][j] += a[i].y * b[j].y;
                    acc[i][j] += a[i].z * b[j].z;
                    acc[i][j] += a[i].w * b[j].w;
                }
        }
        __syncthreads();
    }
#pragma unroll
    for (int i = 0; i < 4; ++i) {
        int bt = bt0 + 4 * ty + i;
        u16 o[4];
#pragma unroll
        for (int j = 0; j < 4; ++j) {
            int col = c0 + 4 * tx + j;
            float x = acc[i][j] + bh[col];
            o[j] = f2b(expf(-fmaxf(x, 0.f)));
        }
        *(uint2*)&gamma[(size_t)bt * Hh + c0 + 4 * tx] = *(uint2*)o;
    }
}

// ---------------------------------------------------------------------------
// Persistent scan kernel, v6: v5 + register-PINNED weight fragments.
// v5's VGPR_Count=80 < 96 (=|Bf|) proved the compiler sank the wfrag loads
// into the t-loop (legal for __restrict__ const loads) -> 24 dependent L2
// loads per step on the MFMA path. asm-volatile "+v" pins make the values
// non-rematerializable: the allocator must keep all 96 regs live across the
// loop. Budget: launch_bounds(512,2) -> 256 VGPR/lane; ~160 fits, occupancy
// unchanged (8 waves/CU). Everything else identical to the passing v5.
// ---------------------------------------------------------------------------
__global__ __launch_bounds__(512, 2) void k_scan(const u16* __restrict__ xrep,
                                                 const u16* __restrict__ mbf,
                                                 const u16* __restrict__ gamma,
                                                 const u16* __restrict__ wfrag,
                                                 const float* __restrict__ biasc,
                                                 int* __restrict__ bar,
                                                 float* __restrict__ hs,
                                                 float* __restrict__ hlast) {
    __shared__ u16  A_s[24 * 64 * 8];   // 24.6 KB, frag-major A tile
    __shared__ float E_s[16][132];      // 8.45 KB, gate preacts

    int tid = threadIdx.x;
    int lane = tid & 63, w = tid >> 6;   // 8 waves

    // ---- XCD-local swizzle (bijective; by-group -> one XCD heuristic) ----
    int L = blockIdx.x + 16 * blockIdx.y;
    int by = (L & 7) + 8 * (L >> 7);
    int bx = (L >> 3) & 15;
    int r0 = by * 16;

    // ---- B fragments: wave w owns cols bx*128 + w*16 + (lane&15) ----
    u32x4 Bf[24];
    const u32x4* wf4 = (const u32x4*)wfrag;
#pragma unroll
    for (int ki = 0; ki < 24; ++ki)
        Bf[ki] = wf4[(size_t)(((bx * 8 + w) * 24 + ki) * 64 + lane)];
    // PIN: force register residency across the t-loop (non-rematerializable).
#pragma unroll
    for (int ki = 0; ki < 24; ++ki)
        asm volatile("" : "+v"(Bf[ki]));

    // staging geometry: frag entry (ki, slot=lane): row = lane&15,
    // kbase = ki*32 + (lane>>4)*8. Waves 0..3 stage x (ki=w), 4..7 stage m
    // (ki=16+w); h entries (ki 4..19) = 2 per thread post-barrier.
    int srow = lane & 15;
    int koff = (lane >> 4) * 8;

    // ---- fixed epilogue mapping: one (row, colH) per thread ----
    int bl = tid >> 5, jh = tid & 31;    // row 0..15, colH 0..31
    int eb = r0 + bl;
    int JH = bx * 32 + jh;
    float4 bi = *(const float4*)&biasc[JH * 4];   // loop-invariant
    float hreg = 0.f;                    // decayed h = h(t-1)*gamma_t (h0 = 0)

    // ---- prologue: stage A tile for t=0 (h region = 0) ----
    {
        if (w < 4) {
            int kb = w * 32 + koff;
            *(uint4*)&A_s[tid * 8] =
                *(const uint4*)&xrep[(size_t)(r0 + srow) * (Tt * Ff) + 0 * Ff + kb];
        } else {
            int kb = (w - 4) * 32 + koff;
            *(uint4*)&A_s[(tid + 1024) * 8] =
                *(const uint4*)&mbf[(size_t)(r0 + srow) * (Tt * Ff) + 0 * Ff + kb];
        }
        uint4 z; z.x = 0; z.y = 0; z.z = 0; z.w = 0;
#pragma unroll
        for (int e = 0; e < 2; ++e) {
            int ki = 4 + 8 * e + w;
            *(uint4*)&A_s[(ki * 64 + lane) * 8] = z;
        }
    }
    __syncthreads();

    for (int t = 0; t < Tt; ++t) {
        // ---- MFMA: 24 k-iters, 1 N-tile per wave, Bf register-resident ----
        f4v acc = {0.f, 0.f, 0.f, 0.f};
#pragma unroll
        for (int ki = 0; ki < 24; ++ki) {
            s8v a = *(const s8v*)&A_s[(ki * 64 + lane) * 8];
            acc = __builtin_amdgcn_mfma_f32_16x16x32_bf16(a, __builtin_bit_cast(s8v, Bf[ki]), acc, 0, 0, 0);
        }

        // ---- C layout (row=(lane>>4)*4+reg, col=lane&15) -> LDS ----
        {
            int colb = w * 16 + (lane & 15);
            int rq = (lane >> 4) * 4;
#pragma unroll
            for (int r = 0; r < 4; ++r)
                E_s[rq + r][colb] = acc[r];
        }
        __syncthreads();   // E_s ready; A_s free (all MFMA reads done)

        // ---- barrier-independent prefetch for t+1 ----
        uint4 g4[2];       // gamma for the 2 h frag-entries this thread stages
        u16 gdec = 0;      // gamma for this thread's epilogue decay
        if (t < Tt - 1) {
            if (w < 4) {
                int kb = w * 32 + koff;
                *(uint4*)&A_s[tid * 8] =
                    *(const uint4*)&xrep[(size_t)(r0 + srow) * (Tt * Ff) + (t + 1) * Ff + kb];
            } else {
                int kb = (w - 4) * 32 + koff;
                *(uint4*)&A_s[(tid + 1024) * 8] =
                    *(const uint4*)&mbf[(size_t)(r0 + srow) * (Tt * Ff) + (t + 1) * Ff + kb];
            }
#pragma unroll
            for (int e = 0; e < 2; ++e) {
                int ki = 4 + 8 * e + w;
                int kh = (ki - 4) * 32 + koff;   // 0..511
                g4[e] = *(const uint4*)&gamma[((size_t)(t + 1) * Bb + (r0 + srow)) * Hh + kh];
            }
            gdec = gamma[((size_t)(t + 1) * Bb + eb) * Hh + JH];
        }

        // ---- gates + h update: ONE (row, colH) per thread ----
        float4 p = *(const float4*)&E_s[bl][jh * 4];
        float rg = 1.f / (1.f + expf(-(p.x + bi.x)));
        float zz = 1.f / (1.f + expf(-(p.y + bi.y)));
        float nn = tanhf(p.z + bi.z + rg * (p.w + bi.w));
        float hn = (1.f - zz) * nn + zz * hreg;

        // publish h_t via RMW (executes at MALL; doubles as the output store)
        __hip_atomic_exchange((u32*)&hs[(size_t)eb * (Tt * Hh) + (size_t)t * Hh + JH],
                              __float_as_uint(hn), __ATOMIC_RELAXED,
                              __HIP_MEMORY_SCOPE_AGENT);

        if (t < Tt - 1) {
            hreg = hn * b2f(gdec);       // decay for next step (f32 in regs)

            // ---- group barrier: all swaps drained, then RMW counter ----
            asm volatile("s_waitcnt vmcnt(0)" ::: "memory");
            __syncthreads();
            if (tid == 0) {
                int* c = &bar[by * 32];
                __hip_atomic_fetch_add(c, 1, __ATOMIC_RELAXED, __HIP_MEMORY_SCOPE_AGENT);
                int target = 16 * (t + 1);
                int iters = 0;
                while (__hip_atomic_fetch_add(c, 0, __ATOMIC_RELAXED,
                                              __HIP_MEMORY_SCOPE_AGENT) < target) {
                    __builtin_amdgcn_s_sleep(1);
                    if (++iters > (1 << 22)) break;   // visible-failure escape
                }
            }
            __syncthreads();

            // ---- stage t+1 h region: 2 frag-entries/thread, batch loads ----
            float4 hb[4];
#pragma unroll
            for (int e = 0; e < 2; ++e) {
                int ki = 4 + 8 * e + w;
                int kh = (ki - 4) * 32 + koff;   // 0..511
                const float* hp = &hs[(size_t)(r0 + srow) * (Tt * Hh) + (size_t)t * Hh + kh];
                hb[2 * e]     = *(const float4*)hp;
                hb[2 * e + 1] = *(const float4*)(hp + 4);
            }
#pragma unroll
            for (int e = 0; e < 2; ++e) {
                int ki = 4 + 8 * e + w;
                float4 h0 = hb[2 * e];
                float4 h1 = hb[2 * e + 1];
                u16 g8[8];
                *(uint4*)g8 = g4[e];
                u16 o[8];
                o[0] = f2b(h0.x * b2f(g8[0])); o[1] = f2b(h0.y * b2f(g8[1]));
                o[2] = f2b(h0.z * b2f(g8[2])); o[3] = f2b(h0.w * b2f(g8[3]));
                o[4] = f2b(h1.x * b2f(g8[4])); o[5] = f2b(h1.y * b2f(g8[5]));
                o[6] = f2b(h1.z * b2f(g8[6])); o[7] = f2b(h1.w * b2f(g8[7]));
                *(uint4*)&A_s[(ki * 64 + lane) * 8] = *(uint4*)o;
            }
            __syncthreads();
        } else {
            hlast[eb * Hh + JH] = hn;
        }
    }
}

extern "C" void kernel_launch(void* const* d_in, const int* in_sizes, int n_in,
                              void* d_out, int out_size, void* d_ws, size_t ws_size,
                              hipStream_t stream) {
    const float* values = (const float*)d_in[0];
    const float* masks  = (const float*)d_in[1];
    const float* deltas = (const float*)d_in[2];
    const float* emean  = (const float*)d_in[3];
    const float* locf   = (const float*)d_in[4];
    const float* wx     = (const float*)d_in[5];
    const float* bxp    = (const float*)d_in[6];
    const float* Wh     = (const float*)d_in[7];
    const float* bh     = (const float*)d_in[8];
    const float* W_ih   = (const float*)d_in[9];
    const float* W_hh   = (const float*)d_in[10];
    const float* b_ih   = (const float*)d_in[11];
    const float* b_hh   = (const float*)d_in[12];

    char* wsb   = (char*)d_ws;
    u16*  gamma = (u16*)(wsb + OFF_GAMMA);
    u16*  xrep  = (u16*)(wsb + OFF_XREP);
    u16*  mbf   = (u16*)(wsb + OFF_MBF);
    u16*  wfrag = (u16*)(wsb + OFF_WFRAG);
    float* biasc = (float*)(wsb + OFF_BIASC);
    int*  bar   = (int*)(wsb + OFF_BAR);
    float* hs    = (float*)d_out;
    float* hlast = hs + (size_t)Bb * Tt * Hh;

    k_zero<<<2, 256, 0, stream>>>(bar, 512);
    k_prep<<<(Bb * Tt * Ff / 4) / 256, 256, 0, stream>>>(values, masks, deltas, locf,
                                                         emean, wx, bxp, xrep, mbf);
    k_gamma<<<dim3((Tt * Bb) / 64, Hh / 64), 256, 0, stream>>>(deltas, Wh, bh, gamma);
    k_wcomb<<<(NC * KTOT / 8) / 256, 256, 0, stream>>>(W_ih, W_hh, b_ih, b_hh, wfrag, biasc);

    k_scan<<<dim3(16, 16), 512, 0, stream>>>(xrep, mbf, gamma, wfrag, biasc,
                                             bar, hs, hlast);
}

// Round 9
// 1662.872 us; speedup vs baseline: 2.3243x; 1.0121x over previous
//
#include <hip/hip_runtime.h>
#include <math.h>

#define Bb 256
#define Tt 256
#define Ff 128
#define Hh 512
#define KTOT 768   // 2F+H
#define NC 2048    // 4*H  (gate cols: colH*4 + {r,z,i_n,h_n})

typedef unsigned short u16;
typedef unsigned int   u32;
typedef unsigned long long u64;
typedef __attribute__((ext_vector_type(8))) short s8v;   // 8 bf16 (4 VGPRs)
typedef __attribute__((ext_vector_type(4))) float f4v;   // 4 fp32 acc
typedef __attribute__((ext_vector_type(4))) u32  u32x4;  // 4 u32 (4 VGPRs)

// ---------------- ws layout (bytes) ----------------
// gamma  : u16 [Tt*Bb*Hh]        = 67,108,864 B   [T,B,H]
// xrep   : u16 [Bb*Tt*Ff]        = 16,777,216 B
// mbf    : u16 [Bb*Tt*Ff]        = 16,777,216 B
// wfrag  : u16 [NC*KTOT]         =  3,145,728 B   frag-major
// biasc  : f32 [NC]              =      8,192 B
// bar    : i32 [16 groups][16 producers][32]  = 32,768 B (flags 128B apart)
// total ≈ 103.9 MB
#define OFF_GAMMA 0ull
#define OFF_XREP  (OFF_GAMMA + 67108864ull)
#define OFF_MBF   (OFF_XREP  + 16777216ull)
#define OFF_WFRAG (OFF_MBF   + 16777216ull)
#define OFF_BIASC (OFF_WFRAG + 3145728ull)
#define OFF_BAR   (OFF_BIASC + 8192ull)

__device__ __forceinline__ u16 f2b(float x) {   // fp32 -> bf16 RNE
    u32 u = __float_as_uint(x);
    return (u16)((u + 0x7FFFu + ((u >> 16) & 1u)) >> 16);
}
__device__ __forceinline__ float b2f(u16 b) {
    return __uint_as_float(((u32)b) << 16);
}

__global__ __launch_bounds__(256) void k_zero(int* p, int n) {
    int i = blockIdx.x * 256 + threadIdx.x;
    if (i < n) p[i] = 0;
}

__device__ __forceinline__ float xrep_one(float x, float m, float d, float l,
                                          float w, float bb, float em) {
    float gx = expf(-fmaxf(d * w + bb, 0.f));
    float xh = gx * l + (1.f - gx) * em;
    return m * x + (1.f - m) * xh;
}

// Elementwise precompute: x_rep and m in bf16, layout [B][T][F].
__global__ __launch_bounds__(256) void k_prep(const float* __restrict__ values,
                                              const float* __restrict__ masks,
                                              const float* __restrict__ deltas,
                                              const float* __restrict__ locf,
                                              const float* __restrict__ emean,
                                              const float* __restrict__ wx,
                                              const float* __restrict__ bxp,
                                              u16* __restrict__ xrep,
                                              u16* __restrict__ mbf) {
    int idx = blockIdx.x * 256 + threadIdx.x;   // < B*T*F/4
    int e = idx * 4;
    int f = e & 127;
    float4 xv = *(const float4*)&values[e];
    float4 mv = *(const float4*)&masks[e];
    float4 dv = *(const float4*)&deltas[e];
    float4 lv = *(const float4*)&locf[e];
    float4 wv = *(const float4*)&wx[f];
    float4 bv = *(const float4*)&bxp[f];
    float4 ev = *(const float4*)&emean[f];
    u16 o[4], mo[4];
    o[0] = f2b(xrep_one(xv.x, mv.x, dv.x, lv.x, wv.x, bv.x, ev.x));
    o[1] = f2b(xrep_one(xv.y, mv.y, dv.y, lv.y, wv.y, bv.y, ev.y));
    o[2] = f2b(xrep_one(xv.z, mv.z, dv.z, lv.z, wv.z, bv.z, ev.z));
    o[3] = f2b(xrep_one(xv.w, mv.w, dv.w, lv.w, wv.w, bv.w, ev.w));
    mo[0] = f2b(mv.x); mo[1] = f2b(mv.y); mo[2] = f2b(mv.z); mo[3] = f2b(mv.w);
    *(uint2*)&xrep[e] = *(uint2*)o;
    *(uint2*)&mbf[e]  = *(uint2*)mo;
}

// Combined weight, frag-major bf16 (unchanged).
__global__ __launch_bounds__(256) void k_wcomb(const float* __restrict__ W_ih,
                                               const float* __restrict__ W_hh,
                                               const float* __restrict__ b_ih,
                                               const float* __restrict__ b_hh,
                                               u16* __restrict__ wfrag,
                                               float* __restrict__ biasc) {
    int G = blockIdx.x * 256 + threadIdx.x;   // < NC*KTOT/8 = 196608
    int lane = G & 63;
    int q = G >> 6;
    int ki = q % 24; q /= 24;
    int nt = q & 1;  q >>= 1;
    int wv = q & 3;  q >>= 2;
    int bx = q;                                // 0..15
    int c = bx * 128 + wv * 32 + nt * 16 + (lane & 15);
    int kbase = ki * 32 + (lane >> 4) * 8;
    int g = c & 3, jH = c >> 2;
    u16 o[8];
#pragma unroll
    for (int j = 0; j < 8; ++j) {
        int k = kbase + j;
        float w;
        if (g < 3) {
            w = W_ih[(size_t)(g * Hh + jH) * KTOT + k];
            if (g < 2 && k >= Ff && k < Ff + Hh) w += W_hh[(size_t)(g * Hh + jH) * Hh + (k - Ff)];
        } else {
            w = (k >= Ff && k < Ff + Hh) ? W_hh[(size_t)(2 * Hh + jH) * Hh + (k - Ff)] : 0.f;
        }
        o[j] = f2b(w);
    }
    *(uint4*)&wfrag[(size_t)G * 8] = *(uint4*)o;
    if (ki == 0 && (lane >> 4) == 0) {
        float bv;
        if (g == 0)      bv = b_ih[jH] + b_hh[jH];
        else if (g == 1) bv = b_ih[Hh + jH] + b_hh[Hh + jH];
        else if (g == 2) bv = b_ih[2 * Hh + jH];
        else             bv = b_hh[2 * Hh + jH];
        biasc[c] = bv;
    }
}

// gamma_h precompute (fp32 compute, bf16 store): [T*B rows] x [H cols], K=128.
__global__ __launch_bounds__(256) void k_gamma(const float* __restrict__ deltas,
                                               const float* __restrict__ Wh,
                                               const float* __restrict__ bh,
                                               u16* __restrict__ gamma) {
    __shared__ float A_s[64][68];
    __shared__ float B_s[64][68];
    int tid = threadIdx.x;
    int tx = tid & 15, ty = tid >> 4;
    int bt0 = blockIdx.x * 64;
    int c0  = blockIdx.y * 64;

    float acc[4][4];
#pragma unroll
    for (int i = 0; i < 4; ++i)
#pragma unroll
        for (int j = 0; j < 4; ++j) acc[i][j] = 0.f;

    for (int kc = 0; kc < 2; ++kc) {
#pragma unroll
        for (int s = 0; s < 4; ++s) {
            int v = tid + s * 256;
            int row = v >> 4, c4 = v & 15, kk = c4 * 4;
            int bt = bt0 + row;
            int b = bt & 255, tt = bt >> 8;
            float4 a = *(const float4*)&deltas[b * (Tt * Ff) + tt * Ff + kc * 64 + kk];
            *(float4*)&A_s[row][kk] = a;
        }
#pragma unroll
        for (int s = 0; s < 4; ++s) {
            int v = tid + s * 256;
            int col = v >> 4, c4 = v & 15, kk = c4 * 4;
            float4 w = *(const float4*)&Wh[(c0 + col) * Ff + kc * 64 + kk];
            *(float4*)&B_s[col][kk] = w;
        }
        __syncthreads();
#pragma unroll
        for (int kk = 0; kk < 64; kk += 4) {
            float4 a[4], b[4];
#pragma unroll
            for (int i = 0; i < 4; ++i) a[i] = *(const float4*)&A_s[4 * ty + i][kk];
#pragma unroll
            for (int j = 0; j < 4; ++j) b[j] = *(const float4*)&B_s[4 * tx + j][kk];
#pragma unroll
            for (int i = 0; i < 4; ++i)
#pragma unroll
                for (int j = 0; j < 4; ++j) {
                    acc[i][j] += a[i].x * b[j].x;
                    acc[i][j] += a[i].y * b[j].y;
                    acc[i][j] += a[i].z * b[j].z;
                    acc[i][j] += a[i].w * b[j].w;
                }
        }
        __syncthreads();
    }
#pragma unroll
    for (int i = 0; i < 4; ++i) {
        int bt = bt0 + 4 * ty + i;
        u16 o[4];
#pragma unroll
        for (int j = 0; j < 4; ++j) {
            int col = c0 + 4 * tx + j;
            float x = acc[i][j] + bh[col];
            o[j] = f2b(expf(-fmaxf(x, 0.f)));
        }
        *(uint2*)&gamma[(size_t)bt * Hh + c0 + 4 * tx] = *(uint2*)o;
    }
}

// ---------------------------------------------------------------------------
// Persistent scan kernel, v7b (byte-identical re-run of v7; round-8 failure
// was infra, per the round-4/5 precedent — audit found no hang path):
// - Per-producer epoch flags (16 lines/group, 128B apart): arrivals are 16
//   parallel uncontended RMWs; detection = wave0 lanes 0..15 probe all 16
//   flags in ONE batched RMW clause per period (__all ballot).
// - x/m MFMA sub-loop (k-slots 0-3,20-23; h-independent) runs between the
//   publish-drain sync and the barrier wait -> post-barrier critical path is
//   only h-stage + 16 h-MFMAs.
// - Paired u64 publishes (even-jh threads, __shfl_down) halve RMW count.
// - Exchange mechanics (MALL RMW publish, virgin-address consume) identical
//   to the passing v3..v6 lineage.
// ---------------------------------------------------------------------------
__global__ __launch_bounds__(512, 2) void k_scan(const u16* __restrict__ xrep,
                                                 const u16* __restrict__ mbf,
                                                 const u16* __restrict__ gamma,
                                                 const u16* __restrict__ wfrag,
                                                 const float* __restrict__ biasc,
                                                 int* __restrict__ bar,
                                                 float* __restrict__ hs,
                                                 float* __restrict__ hlast) {
    __shared__ u16  A_s[24 * 64 * 8];   // 24.6 KB, frag-major A tile
    __shared__ float E_s[16][132];      // 8.45 KB, gate preacts

    int tid = threadIdx.x;
    int lane = tid & 63, w = tid >> 6;   // 8 waves

    // ---- XCD-local swizzle (bijective; by-group -> one XCD heuristic) ----
    int L = blockIdx.x + 16 * blockIdx.y;
    int by = (L & 7) + 8 * (L >> 7);
    int bx = (L >> 3) & 15;
    int r0 = by * 16;

    // ---- B fragments: wave w owns cols bx*128 + w*16 + (lane&15) ----
    u32x4 Bf[24];
    const u32x4* wf4 = (const u32x4*)wfrag;
#pragma unroll
    for (int ki = 0; ki < 24; ++ki)
        Bf[ki] = wf4[(size_t)(((bx * 8 + w) * 24 + ki) * 64 + lane)];
#pragma unroll
    for (int ki = 0; ki < 24; ++ki)
        asm volatile("" : "+v"(Bf[ki]));

    // staging geometry: frag entry (ki, slot=lane): row = lane&15,
    // kbase = ki*32 + (lane>>4)*8.
    int srow = lane & 15;
    int koff = (lane >> 4) * 8;

    // ---- fixed epilogue mapping: one (row, colH) per thread ----
    int bl = tid >> 5, jh = tid & 31;    // row 0..15, colH 0..31
    int eb = r0 + bl;
    int JH = bx * 32 + jh;
    float4 bi = *(const float4*)&biasc[JH * 4];   // loop-invariant
    float hreg = 0.f;                    // decayed h = h(t-1)*gamma_t (h0 = 0)

    // ---- prologue: stage x(0)/m(0), zero h region ----
    {
        if (w < 4) {
            int kb = w * 32 + koff;
            *(uint4*)&A_s[tid * 8] =
                *(const uint4*)&xrep[(size_t)(r0 + srow) * (Tt * Ff) + 0 * Ff + kb];
        } else {
            int kb = (w - 4) * 32 + koff;
            *(uint4*)&A_s[(tid + 1024) * 8] =
                *(const uint4*)&mbf[(size_t)(r0 + srow) * (Tt * Ff) + 0 * Ff + kb];
        }
        uint4 z; z.x = 0; z.y = 0; z.z = 0; z.w = 0;
#pragma unroll
        for (int e = 0; e < 2; ++e) {
            int ki = 4 + 8 * e + w;
            *(uint4*)&A_s[(ki * 64 + lane) * 8] = z;
        }
    }
    __syncthreads();

    // ---- pre-accumulate x/m MFMAs for t=0 ----
    f4v acc = {0.f, 0.f, 0.f, 0.f};
#pragma unroll
    for (int s = 0; s < 8; ++s) {
        int ki = (s < 4) ? s : (16 + s);       // 0,1,2,3,20,21,22,23
        s8v a = *(const s8v*)&A_s[(ki * 64 + lane) * 8];
        acc = __builtin_amdgcn_mfma_f32_16x16x32_bf16(a, __builtin_bit_cast(s8v, Bf[ki]), acc, 0, 0, 0);
    }

    for (int t = 0; t < Tt; ++t) {
        // ---- h MFMAs (k-slots 4..19); x/m already accumulated ----
#pragma unroll
        for (int ki = 4; ki < 20; ++ki) {
            s8v a = *(const s8v*)&A_s[(ki * 64 + lane) * 8];
            acc = __builtin_amdgcn_mfma_f32_16x16x32_bf16(a, __builtin_bit_cast(s8v, Bf[ki]), acc, 0, 0, 0);
        }

        // ---- C layout (row=(lane>>4)*4+reg, col=lane&15) -> LDS ----
        {
            int colb = w * 16 + (lane & 15);
            int rq = (lane >> 4) * 4;
#pragma unroll
            for (int r = 0; r < 4; ++r)
                E_s[rq + r][colb] = acc[r];
        }
        __syncthreads();   // E_s ready; A_s x/m free (consumed for acc of t)

        // ---- barrier-independent prefetch for t+1 ----
        uint4 g4[2];       // gamma for the 2 h frag-entries this thread stages
        u16 gdec = 0;      // gamma for this thread's epilogue decay
        if (t < Tt - 1) {
            if (w < 4) {
                int kb = w * 32 + koff;
                *(uint4*)&A_s[tid * 8] =
                    *(const uint4*)&xrep[(size_t)(r0 + srow) * (Tt * Ff) + (t + 1) * Ff + kb];
            } else {
                int kb = (w - 4) * 32 + koff;
                *(uint4*)&A_s[(tid + 1024) * 8] =
                    *(const uint4*)&mbf[(size_t)(r0 + srow) * (Tt * Ff) + (t + 1) * Ff + kb];
            }
#pragma unroll
            for (int e = 0; e < 2; ++e) {
                int ki = 4 + 8 * e + w;
                int kh = (ki - 4) * 32 + koff;   // 0..511
                g4[e] = *(const uint4*)&gamma[((size_t)(t + 1) * Bb + (r0 + srow)) * Hh + kh];
            }
            gdec = gamma[((size_t)(t + 1) * Bb + eb) * Hh + JH];
        }

        // ---- gates + h update: ONE (row, colH) per thread ----
        float4 p = *(const float4*)&E_s[bl][jh * 4];
        float rg = 1.f / (1.f + expf(-(p.x + bi.x)));
        float zz = 1.f / (1.f + expf(-(p.y + bi.y)));
        float nn = tanhf(p.z + bi.z + rg * (p.w + bi.w));
        float hn = (1.f - zz) * nn + zz * hreg;

        // ---- paired u64 publish via MALL RMW (even-jh threads) ----
        float hn_hi = __shfl_down(hn, 1);
        if ((jh & 1) == 0) {
            union { float f[2]; u64 u; } pk;
            pk.f[0] = hn; pk.f[1] = hn_hi;
            __hip_atomic_exchange((u64*)&hs[(size_t)eb * (Tt * Hh) + (size_t)t * Hh + JH],
                                  pk.u, __ATOMIC_RELAXED, __HIP_MEMORY_SCOPE_AGENT);
        }

        if (t < Tt - 1) {
            hreg = hn * b2f(gdec);       // decay for next step (f32 in regs)

            // ---- drain publishes + prefetches; make A_s x/m(t+1) visible ----
            asm volatile("s_waitcnt vmcnt(0)" ::: "memory");
            __syncthreads();

            int target = t + 1;
            // arrival: own flag, own line (uncontended)
            if (tid == 0)
                __hip_atomic_exchange(&bar[by * 512 + bx * 32], target,
                                      __ATOMIC_RELAXED, __HIP_MEMORY_SCOPE_AGENT);

            // ---- x/m MFMAs for t+1 overlap the barrier ----
            f4v acc2 = {0.f, 0.f, 0.f, 0.f};
#pragma unroll
            for (int s = 0; s < 8; ++s) {
                int ki = (s < 4) ? s : (16 + s);
                s8v a = *(const s8v*)&A_s[(ki * 64 + lane) * 8];
                acc2 = __builtin_amdgcn_mfma_f32_16x16x32_bf16(a, __builtin_bit_cast(s8v, Bf[ki]), acc2, 0, 0, 0);
            }

            // ---- detection: wave0 lanes 0..15 probe all 16 flags per RT ----
            if (w == 0) {
                int iters = 0;
                while (true) {
                    int v = target;
                    if (lane < 16)
                        v = __hip_atomic_fetch_add(&bar[by * 512 + lane * 32], 0,
                                                   __ATOMIC_RELAXED, __HIP_MEMORY_SCOPE_AGENT);
                    if (__all(v >= target)) break;
                    __builtin_amdgcn_s_sleep(1);
                    if (++iters > (1 << 20)) break;   // visible-failure escape
                }
            }
            __syncthreads();

            // ---- stage hdec(t+1): batch loads, convert, ds_write ----
            float4 hb[4];
#pragma unroll
            for (int e = 0; e < 2; ++e) {
                int ki = 4 + 8 * e + w;
                int kh = (ki - 4) * 32 + koff;   // 0..511
                const float* hp = &hs[(size_t)(r0 + srow) * (Tt * Hh) + (size_t)t * Hh + kh];
                hb[2 * e]     = *(const float4*)hp;
                hb[2 * e + 1] = *(const float4*)(hp + 4);
            }
#pragma unroll
            for (int e = 0; e < 2; ++e) {
                int ki = 4 + 8 * e + w;
                float4 h0 = hb[2 * e];
                float4 h1 = hb[2 * e + 1];
                u16 g8[8];
                *(uint4*)g8 = g4[e];
                u16 o[8];
                o[0] = f2b(h0.x * b2f(g8[0])); o[1] = f2b(h0.y * b2f(g8[1]));
                o[2] = f2b(h0.z * b2f(g8[2])); o[3] = f2b(h0.w * b2f(g8[3]));
                o[4] = f2b(h1.x * b2f(g8[4])); o[5] = f2b(h1.y * b2f(g8[5]));
                o[6] = f2b(h1.z * b2f(g8[6])); o[7] = f2b(h1.w * b2f(g8[7]));
                *(uint4*)&A_s[(ki * 64 + lane) * 8] = *(uint4*)o;
            }
            __syncthreads();
            acc = acc2;
        } else {
            hlast[eb * Hh + JH] = hn;
        }
    }
}

extern "C" void kernel_launch(void* const* d_in, const int* in_sizes, int n_in,
                              void* d_out, int out_size, void* d_ws, size_t ws_size,
                              hipStream_t stream) {
    const float* values = (const float*)d_in[0];
    const float* masks  = (const float*)d_in[1];
    const float* deltas = (const float*)d_in[2];
    const float* emean  = (const float*)d_in[3];
    const float* locf   = (const float*)d_in[4];
    const float* wx     = (const float*)d_in[5];
    const float* bxp    = (const float*)d_in[6];
    const float* Wh     = (const float*)d_in[7];
    const float* bh     = (const float*)d_in[8];
    const float* W_ih   = (const float*)d_in[9];
    const float* W_hh   = (const float*)d_in[10];
    const float* b_ih   = (const float*)d_in[11];
    const float* b_hh   = (const float*)d_in[12];

    char* wsb   = (char*)d_ws;
    u16*  gamma = (u16*)(wsb + OFF_GAMMA);
    u16*  xrep  = (u16*)(wsb + OFF_XREP);
    u16*  mbf   = (u16*)(wsb + OFF_MBF);
    u16*  wfrag = (u16*)(wsb + OFF_WFRAG);
    float* biasc = (float*)(wsb + OFF_BIASC);
    int*  bar   = (int*)(wsb + OFF_BAR);
    float* hs    = (float*)d_out;
    float* hlast = hs + (size_t)Bb * Tt * Hh;

    k_zero<<<32, 256, 0, stream>>>(bar, 16 * 512);
    k_prep<<<(Bb * Tt * Ff / 4) / 256, 256, 0, stream>>>(values, masks, deltas, locf,
                                                         emean, wx, bxp, xrep, mbf);
    k_gamma<<<dim3((Tt * Bb) / 64, Hh / 64), 256, 0, stream>>>(deltas, Wh, bh, gamma);
    k_wcomb<<<(NC * KTOT / 8) / 256, 256, 0, stream>>>(W_ih, W_hh, b_ih, b_hh, wfrag, biasc);

    k_scan<<<dim3(16, 16), 512, 0, stream>>>(xrep, mbf, gamma, wfrag, biasc,
                                             bar, hs, hlast);
}